// Round 6
// baseline (1096.605 us; speedup 1.0000x reference)
//
#include <hip/hip_runtime.h>

#define NN 100000
#define NE 500000
#define D 128
#define EPS 1e-5f
#define SLOPE 0.01f

typedef short bf16x8 __attribute__((ext_vector_type(8)));
typedef float f32x4 __attribute__((ext_vector_type(4)));

__device__ __forceinline__ ushort f2bf(float x) {
  uint u = __float_as_uint(x);
  u += 0x7FFF + ((u >> 16) & 1);
  return (ushort)(u >> 16);
}
__device__ __forceinline__ float bf2f(ushort h) {
  return __uint_as_float(((uint)h) << 16);
}

// ---------------- CSR build: count both edge types in one kernel ----------------
__global__ void count_deg2(const int* __restrict__ ei1, const int* __restrict__ ei2,
                           int E, int* __restrict__ deg1, int* __restrict__ deg2) {
  int i = blockIdx.x * 256 + threadIdx.x;
  if (i < E) atomicAdd(&deg1[ei1[E + i]], 1);          // dst of type 1
  else if (i < 2 * E) atomicAdd(&deg2[ei2[E + (i - E)]], 1);
}

// ---- single-block two-phase exclusive scan for both deg arrays ----
__global__ __launch_bounds__(1024) void scan_csr(
    const int* __restrict__ deg1, const int* __restrict__ deg2,
    int* __restrict__ rp1, int* __restrict__ fl1, float* __restrict__ inv1,
    int* __restrict__ rp2, int* __restrict__ fl2, float* __restrict__ inv2,
    int n, int Etot) {
  __shared__ int lds[1024];
  int t = threadIdx.x;
  int per = (n + 1023) / 1024;
#pragma unroll 1
  for (int a = 0; a < 2; ++a) {
    const int* deg = a ? deg2 : deg1;
    int* rp = a ? rp2 : rp1;
    int* fl = a ? fl2 : fl1;
    float* inv = a ? inv2 : inv1;
    int beg = t * per;
    int end = beg + per < n ? beg + per : n;
    int s = 0;
    for (int i = beg; i < end; ++i) s += deg[i];
    lds[t] = s;
    __syncthreads();
#pragma unroll 1
    for (int d2 = 1; d2 < 1024; d2 <<= 1) {
      int v = lds[t];
      int u = (t >= d2) ? lds[t - d2] : 0;
      __syncthreads();
      lds[t] = v + u;
      __syncthreads();
    }
    int run = lds[t] - s;  // exclusive prefix of this thread's chunk
    for (int i = beg; i < end; ++i) {
      int dv = deg[i];
      rp[i] = run;
      fl[i] = run;
      inv[i] = 1.0f / (float)(dv < 1 ? 1 : dv);
      run += dv;
    }
    if (t == 0) rp[n] = Etot;
    __syncthreads();
  }
}

__global__ void fill_csr2(const int* __restrict__ ei1, const int* __restrict__ ei2,
                          int* __restrict__ fl1, int* __restrict__ fl2,
                          int* __restrict__ col1, int* __restrict__ col2, int E) {
  int i = blockIdx.x * 256 + threadIdx.x;
  if (i < E) {
    int p = atomicAdd(&fl1[ei1[E + i]], 1);
    col1[p] = ei1[i];
  } else if (i < 2 * E) {
    int j = i - E;
    int p = atomicAdd(&fl2[ei2[E + j]], 1);
    col2[p] = ei2[j];
  }
}

// ------------- weight pack (both layers): B-fragment order, hi/lo split -------------
__global__ void wpack2(const float* __restrict__ W1n1, const float* __restrict__ W1n2,
                       const float* __restrict__ W1s1, const float* __restrict__ W1s2,
                       const float* __restrict__ W2n1, const float* __restrict__ W2n2,
                       const float* __restrict__ W2s1, const float* __restrict__ W2s2,
                       bf16x8* __restrict__ Wh1, bf16x8* __restrict__ Wl1,
                       bf16x8* __restrict__ Wh2, bf16x8* __restrict__ Wl2) {
  int bid = blockIdx.x;            // 0..47
  int layer = bid >= 24;
  int ct = bid - layer * 24;
  const float* Wn1 = layer ? W2n1 : W1n1;
  const float* Wn2 = layer ? W2n2 : W1n2;
  const float* Ws1 = layer ? W2s1 : W1s1;
  const float* Ws2 = layer ? W2s2 : W1s2;
  bf16x8* Wh = layer ? Wh2 : Wh1;
  bf16x8* Wl = layer ? Wl2 : Wl1;
  int ks = threadIdx.x >> 6;
  int l = threadIdx.x & 63;
  int col = (ct & 7) * 16 + (l & 15);
  int k0 = ks * 32 + (l >> 4) * 8;
  bf16x8 hv, lv;
#pragma unroll
  for (int j = 0; j < 8; ++j) {
    int k = k0 + j;
    float v;
    if (ct < 8)       v = Wn1[k * D + col];
    else if (ct < 16) v = Wn2[k * D + col];
    else              v = Ws1[k * D + col] + Ws2[k * D + col];
    ushort h = f2bf(v);
    float r = v - bf2f(h);
    hv[j] = (short)h;
    lv[j] = (short)f2bf(r);
  }
  int idx = (ct * 4 + ks) * 64 + l;
  Wh[idx] = hv;
  Wl[idx] = lv;
}

// ---------------- X pack into A-fragment order (hi/lo split) ----------------
__global__ void xpack(const float* __restrict__ X, bf16x8* __restrict__ Xh,
                      bf16x8* __restrict__ Xl, int M) {
  int g = blockIdx.x;
  int ks = threadIdx.x >> 6;
  int l = threadIdx.x & 63;
  int row = g * 16 + (l & 15);
  int c0 = ks * 32 + (l >> 4) * 8;
  bf16x8 hv, lv;
  if (row < M) {
    float4 a = *reinterpret_cast<const float4*>(X + (size_t)row * D + c0);
    float4 b = *reinterpret_cast<const float4*>(X + (size_t)row * D + c0 + 4);
    float xs[8] = {a.x, a.y, a.z, a.w, b.x, b.y, b.z, b.w};
#pragma unroll
    for (int j = 0; j < 8; ++j) {
      ushort h = f2bf(xs[j]);
      float r = xs[j] - bf2f(h);
      hv[j] = (short)h;
      lv[j] = (short)f2bf(r);
    }
  } else {
#pragma unroll
    for (int j = 0; j < 8; ++j) { hv[j] = 0; lv[j] = 0; }
  }
  int idx = (g * 4 + ks) * 64 + l;
  Xh[idx] = hv;
  Xl[idx] = lv;
}

// ------- MFMA GEMM: 32 rows/block, 8 waves, 3 col-tiles/wave (acc 24 AGPR) -------
__global__ __launch_bounds__(512) void gemm_mfma(
    const bf16x8* __restrict__ Xh, const bf16x8* __restrict__ Xl,
    const bf16x8* __restrict__ Wh, const bf16x8* __restrict__ Wl,
    ushort* __restrict__ Hn1b, ushort* __restrict__ Hn2b,
    ushort* __restrict__ Hsb, int M) {
  int w = __builtin_amdgcn_readfirstlane(threadIdx.x >> 6);  // 0..7
  int l = threadIdx.x & 63;
  int rb = blockIdx.x;   // 32-row tile

  f32x4 acc[2][3];
#pragma unroll
  for (int rt = 0; rt < 2; ++rt)
#pragma unroll
    for (int i = 0; i < 3; ++i)
      acc[rt][i] = (f32x4){0.f, 0.f, 0.f, 0.f};

#pragma unroll
  for (int ks = 0; ks < 4; ++ks) {
    bf16x8 Ah[2], Al[2];
#pragma unroll
    for (int rt = 0; rt < 2; ++rt) {
      int gi = ((rb * 2 + rt) * 4 + ks) * 64 + l;
      Ah[rt] = Xh[gi];
      Al[rt] = Xl[gi];
    }
#pragma unroll
    for (int i = 0; i < 3; ++i) {
      int ct = w + 8 * i;
      int wi = (ct * 4 + ks) * 64 + l;
      bf16x8 bh = Wh[wi];
      bf16x8 bl = Wl[wi];
#pragma unroll
      for (int rt = 0; rt < 2; ++rt) {
        acc[rt][i] = __builtin_amdgcn_mfma_f32_16x16x32_bf16(Ah[rt], bh, acc[rt][i], 0, 0, 0);
        acc[rt][i] = __builtin_amdgcn_mfma_f32_16x16x32_bf16(Ah[rt], bl, acc[rt][i], 0, 0, 0);
        acc[rt][i] = __builtin_amdgcn_mfma_f32_16x16x32_bf16(Al[rt], bh, acc[rt][i], 0, 0, 0);
      }
    }
  }

  int cq = l & 15;
  int rq = (l >> 4) * 4;
#pragma unroll
  for (int i = 0; i < 3; ++i) {
    int ct = w + 8 * i;  // wave-uniform
    ushort* dstbuf = (ct < 8) ? Hn1b : (ct < 16) ? Hn2b : Hsb;
    int cc = (ct & 7) * 16 + cq;
#pragma unroll
    for (int rt = 0; rt < 2; ++rt) {
      int R0 = rb * 32 + rt * 16 + rq;
#pragma unroll
      for (int r = 0; r < 4; ++r) {
        int R = R0 + r;
        if (R < M) dstbuf[(size_t)R * D + cc] = f2bf(acc[rt][i][r]);
      }
    }
  }
}

// ---- fused aggregation + BN partial stats ----
// Hsb[n] += inv1*sum Hn1b[col1] + inv2*sum Hn2b[col2]; block-reduced sums/sumsq
// accumulate into 64-slot partial buffers (zeroed by memset / bn_finalize).
__global__ __launch_bounds__(256) void fused_agg(
    ushort* __restrict__ Hsb, const ushort* __restrict__ Hn1b,
    const ushort* __restrict__ Hn2b,
    const int* __restrict__ rp1, const int* __restrict__ col1,
    const float* __restrict__ inv1,
    const int* __restrict__ rp2, const int* __restrict__ col2,
    const float* __restrict__ inv2,
    float* __restrict__ part_s, float* __restrict__ part_q, int Nn) {
  __shared__ float lds_s[4][128];
  __shared__ float lds_q[4][128];
  int wv = threadIdx.x >> 6;
  int l = threadIdx.x & 63;
  int n = blockIdx.x * 4 + wv;
  int t2 = l * 2;
  float c0 = 0.f, c1 = 0.f;
  if (n < Nn) {
    int b1 = rp1[n], e1 = rp1[n + 1];
    int b2 = rp2[n], e2 = rp2[n + 1];
    float i1 = inv1[n], i2 = inv2[n];
    int len1 = e1 - b1, len2 = e2 - b2;
    int lmax = len1 > len2 ? len1 : len2;
    float pa = 0.f, pb = 0.f, qa = 0.f, qb = 0.f;
    for (int j0 = 0; j0 < lmax; j0 += 8) {
      int i1x[8], i2x[8];
      float m1[8], m2[8];
#pragma unroll
      for (int k = 0; k < 8; ++k) {
        int a = j0 + k;
        i1x[k] = (len1 > 0) ? col1[b1 + (a < len1 ? a : len1 - 1)] : 0;
        i2x[k] = (len2 > 0) ? col2[b2 + (a < len2 ? a : len2 - 1)] : 0;
        m1[k] = (a < len1) ? 1.f : 0.f;
        m2[k] = (a < len2) ? 1.f : 0.f;
      }
      uint v1[8], v2[8];
#pragma unroll
      for (int k = 0; k < 8; ++k) {
        v1[k] = *reinterpret_cast<const uint*>(Hn1b + (size_t)i1x[k] * D + t2);
        v2[k] = *reinterpret_cast<const uint*>(Hn2b + (size_t)i2x[k] * D + t2);
      }
#pragma unroll
      for (int k = 0; k < 8; ++k) {
        pa = fmaf(m1[k], bf2f((ushort)(v1[k] & 0xFFFF)), pa);
        pb = fmaf(m1[k], bf2f((ushort)(v1[k] >> 16)), pb);
        qa = fmaf(m2[k], bf2f((ushort)(v2[k] & 0xFFFF)), qa);
        qb = fmaf(m2[k], bf2f((ushort)(v2[k] >> 16)), qb);
      }
    }
    uint sv = *reinterpret_cast<const uint*>(Hsb + (size_t)n * D + t2);
    c0 = bf2f((ushort)(sv & 0xFFFF)) + pa * i1 + qa * i2;
    c1 = bf2f((ushort)(sv >> 16)) + pb * i1 + qb * i2;
    ushort h0 = f2bf(c0), h1 = f2bf(c1);
    *reinterpret_cast<uint*>(Hsb + (size_t)n * D + t2) = ((uint)h1 << 16) | (uint)h0;
    c0 = bf2f(h0);  // stats on the stored (rounded) values: self-consistent BN
    c1 = bf2f(h1);
  }
  lds_s[wv][t2] = c0;
  lds_s[wv][t2 + 1] = c1;
  lds_q[wv][t2] = c0 * c0;
  lds_q[wv][t2 + 1] = c1 * c1;
  __syncthreads();
  if (threadIdx.x < 128) {
    int c = threadIdx.x;
    float s = lds_s[0][c] + lds_s[1][c] + lds_s[2][c] + lds_s[3][c];
    float q = lds_q[0][c] + lds_q[1][c] + lds_q[2][c] + lds_q[3][c];
    int slot = (blockIdx.x & 63) * 128 + c;
    atomicAdd(&part_s[slot], s);
    atomicAdd(&part_q[slot], q);
  }
}

// ---- finalize BN: partials -> per-column affine coef; re-zero partials ----
__global__ void bn_finalize(float* __restrict__ part_s, float* __restrict__ part_q,
                            const float* __restrict__ g, const float* __restrict__ b,
                            float* __restrict__ coef, float invM) {
  int c = threadIdx.x;
  if (c >= D) return;
  float s = 0.f, q = 0.f;
#pragma unroll 4
  for (int i = 0; i < 64; ++i) {
    s += part_s[i * 128 + c];
    part_s[i * 128 + c] = 0.f;
    q += part_q[i * 128 + c];
    part_q[i * 128 + c] = 0.f;
  }
  float mean = s * invM;
  float var = q * invM - mean * mean;
  float sc = rsqrtf(var + EPS) * g[c];
  coef[c] = sc;
  coef[D + c] = b[c] - mean * sc;
}

// ---- BN(affine)+LeakyReLU applied to Hsb; split-pack into A-fragment order ----
__global__ void bn_apply_pack(const ushort* __restrict__ Hsb, const float* __restrict__ coef,
                              bf16x8* __restrict__ Ah, bf16x8* __restrict__ Al, int M) {
  int g = blockIdx.x;
  int ks = threadIdx.x >> 6;
  int l = threadIdx.x & 63;
  int row = g * 16 + (l & 15);
  int c0 = ks * 32 + (l >> 4) * 8;
  bf16x8 hv, lv;
  if (row < M) {
    bf16x8 in = *reinterpret_cast<const bf16x8*>(Hsb + (size_t)row * D + c0);
#pragma unroll
    for (int j = 0; j < 8; ++j) {
      int c = c0 + j;
      float v = fmaf(bf2f((ushort)in[j]), coef[c], coef[D + c]);
      v = v > 0.f ? v : SLOPE * v;
      ushort h = f2bf(v);
      float r = v - bf2f(h);
      hv[j] = (short)h;
      lv[j] = (short)f2bf(r);
    }
  } else {
#pragma unroll
    for (int j = 0; j < 8; ++j) { hv[j] = 0; lv[j] = 0; }
  }
  int idx = (g * 4 + ks) * 64 + l;
  Ah[idx] = hv;
  Al[idx] = lv;
}

// ------- edge-label dots: gather bf16 rows, BN affine applied inline -------
__global__ void edge_dot_bn(const ushort* __restrict__ Hb, const float* __restrict__ coef,
                            const int* __restrict__ ea, const int* __restrict__ eb,
                            float* __restrict__ out, int EL) {
  int tt = blockIdx.x * 256 + threadIdx.x;
  int e = tt >> 4, l = tt & 15;
  if (e >= EL) return;
  int cb = l * 8;
  float4 sc0 = *reinterpret_cast<const float4*>(coef + cb);
  float4 sc1 = *reinterpret_cast<const float4*>(coef + cb + 4);
  float4 sh0 = *reinterpret_cast<const float4*>(coef + D + cb);
  float4 sh1 = *reinterpret_cast<const float4*>(coef + D + cb + 4);
  float sc[8] = {sc0.x, sc0.y, sc0.z, sc0.w, sc1.x, sc1.y, sc1.z, sc1.w};
  float sh[8] = {sh0.x, sh0.y, sh0.z, sh0.w, sh1.x, sh1.y, sh1.z, sh1.w};
  bf16x8 av = *reinterpret_cast<const bf16x8*>(Hb + (size_t)ea[e] * D + cb);
  bf16x8 bv = *reinterpret_cast<const bf16x8*>(Hb + (size_t)eb[e] * D + cb);
  float d = 0.f;
#pragma unroll
  for (int j = 0; j < 8; ++j) {
    float fa = fmaf(bf2f((ushort)av[j]), sc[j], sh[j]);
    float fb = fmaf(bf2f((ushort)bv[j]), sc[j], sh[j]);
    d = fmaf(fa, fb, d);
  }
  d += __shfl_xor(d, 1);
  d += __shfl_xor(d, 2);
  d += __shfl_xor(d, 4);
  d += __shfl_xor(d, 8);
  if (l == 0) out[e] = d;
}

// ---------------- launch ----------------
extern "C" void kernel_launch(void* const* d_in, const int* in_sizes, int n_in,
                              void* d_out, int out_size, void* d_ws, size_t ws_size,
                              hipStream_t stream) {
  const float* x    = (const float*)d_in[0];
  const int* ei1    = (const int*)d_in[1];
  const int* ei2    = (const int*)d_in[2];
  const int* eli    = (const int*)d_in[3];
  const float* W1n1 = (const float*)d_in[4];
  const float* W1s1 = (const float*)d_in[5];
  const float* W1n2 = (const float*)d_in[6];
  const float* W1s2 = (const float*)d_in[7];
  const float* W2n1 = (const float*)d_in[8];
  const float* W2s1 = (const float*)d_in[9];
  const float* W2n2 = (const float*)d_in[10];
  const float* W2s2 = (const float*)d_in[11];
  const float* g1   = (const float*)d_in[12];
  const float* b1   = (const float*)d_in[13];
  const float* g2   = (const float*)d_in[14];
  const float* b2   = (const float*)d_in[15];
  float* out = (float*)d_out;

  const int N = NN, E = NE;
  const int EL = in_sizes[3] / 2;
  const int RB = (N + 31) / 32;       // 32-row gemm blocks (3125)
  const int G = RB * 2;               // 16-row A-fragment tiles (6250)

  char* w = (char*)d_ws;
  // zeroed region (one memset): deg1, deg2, part_s, part_q
  int* deg1 = (int*)w; w += (size_t)N * 4;
  int* deg2 = (int*)w; w += (size_t)N * 4;
  float* part_s = (float*)w; w += (size_t)64 * 128 * 4;
  float* part_q = (float*)w; w += (size_t)64 * 128 * 4;
  size_t zbytes = (size_t)(2 * N + 2 * 64 * 128) * 4;

  bf16x8* Xh = (bf16x8*)w; w += (size_t)G * 4 * 64 * 16;
  bf16x8* Xl = (bf16x8*)w; w += (size_t)G * 4 * 64 * 16;
  ushort* Hn1b = (ushort*)w; w += (size_t)N * D * 2;
  ushort* Hn2b = (ushort*)w; w += (size_t)N * D * 2;
  ushort* Hsb  = (ushort*)w; w += (size_t)N * D * 2;
  bf16x8* Wh1 = (bf16x8*)w; w += (size_t)24 * 4 * 64 * 16;
  bf16x8* Wl1 = (bf16x8*)w; w += (size_t)24 * 4 * 64 * 16;
  bf16x8* Wh2 = (bf16x8*)w; w += (size_t)24 * 4 * 64 * 16;
  bf16x8* Wl2 = (bf16x8*)w; w += (size_t)24 * 4 * 64 * 16;
  int* rp1  = (int*)w; w += (size_t)(N + 1) * 4;
  int* rp2  = (int*)w; w += (size_t)(N + 1) * 4;
  int* fl1  = (int*)w; w += (size_t)N * 4;
  int* fl2  = (int*)w; w += (size_t)N * 4;
  int* col1 = (int*)w; w += (size_t)E * 4;
  int* col2 = (int*)w; w += (size_t)E * 4;
  float* inv1 = (float*)w; w += (size_t)N * 4;
  float* inv2 = (float*)w; w += (size_t)N * 4;
  float* coef1 = (float*)w; w += 2 * D * 4;
  float* coef2 = (float*)w; w += 2 * D * 4;

  hipMemsetAsync(deg1, 0, zbytes, stream);

  int e2b = (2 * E + 255) / 256;
  count_deg2<<<e2b, 256, 0, stream>>>(ei1, ei2, E, deg1, deg2);
  scan_csr<<<1, 1024, 0, stream>>>(deg1, deg2, rp1, fl1, inv1, rp2, fl2, inv2, N, E);
  fill_csr2<<<e2b, 256, 0, stream>>>(ei1, ei2, fl1, fl2, col1, col2, E);

  wpack2<<<48, 256, 0, stream>>>(W1n1, W1n2, W1s1, W1s2, W2n1, W2n2, W2s1, W2s2,
                                 Wh1, Wl1, Wh2, Wl2);
  xpack<<<G, 256, 0, stream>>>(x, Xh, Xl, N);

  int agb = (N + 3) / 4;

  // ---- Layer 1 ----
  gemm_mfma<<<RB, 512, 0, stream>>>(Xh, Xl, Wh1, Wl1, Hn1b, Hn2b, Hsb, N);
  fused_agg<<<agb, 256, 0, stream>>>(Hsb, Hn1b, Hn2b, rp1, col1, inv1, rp2, col2, inv2,
                                     part_s, part_q, N);
  bn_finalize<<<1, 128, 0, stream>>>(part_s, part_q, g1, b1, coef1, 1.0f / N);
  bn_apply_pack<<<G, 256, 0, stream>>>(Hsb, coef1, Xh, Xl, N);  // overwrite X packs

  // ---- Layer 2 ----
  gemm_mfma<<<RB, 512, 0, stream>>>(Xh, Xl, Wh2, Wl2, Hn1b, Hn2b, Hsb, N);
  fused_agg<<<agb, 256, 0, stream>>>(Hsb, Hn1b, Hn2b, rp1, col1, inv1, rp2, col2, inv2,
                                     part_s, part_q, N);
  bn_finalize<<<1, 128, 0, stream>>>(part_s, part_q, g2, b2, coef2, 1.0f / N);

  // ---- edge-label dots (bf16 gathers, BN affine fused) ----
  int db = (int)(((size_t)EL * 16 + 255) / 256);
  edge_dot_bn<<<db, 256, 0, stream>>>(Hsb, coef2, eli, eli + EL, out, EL);
}

// Round 8
// 553.007 us; speedup vs baseline: 1.9830x; 1.9830x over previous
//
#include <hip/hip_runtime.h>

#define NN 100000
#define NE 500000
#define D 128
#define EPS 1e-5f
#define SLOPE 0.01f

typedef short bf16x8 __attribute__((ext_vector_type(8)));
typedef float f32x4 __attribute__((ext_vector_type(4)));

__device__ __forceinline__ ushort f2bf(float x) {
  uint u = __float_as_uint(x);
  u += 0x7FFF + ((u >> 16) & 1);
  return (ushort)(u >> 16);
}
__device__ __forceinline__ float bf2f(ushort h) {
  return __uint_as_float(((uint)h) << 16);
}

// ---------------- CSR build: count both edge types in one kernel ----------------
// deg is a combined [2N] array: deg1 = deg, deg2 = deg + N.
__global__ void count_deg2(const int* __restrict__ ei1, const int* __restrict__ ei2,
                           int E, int* __restrict__ deg, int Nn) {
  int i = blockIdx.x * 256 + threadIdx.x;
  if (i < E) atomicAdd(&deg[ei1[E + i]], 1);
  else if (i < 2 * E) atomicAdd(&deg[Nn + ei2[E + (i - E)]], 1);
}

// ---- combined multi-block exclusive scan over deg[2N] ----
__global__ void scan_block_sums(const int* __restrict__ deg, int* __restrict__ bsums, int n2) {
  __shared__ int red[256];
  int base = blockIdx.x * 1024;
  int s = 0;
  for (int i = threadIdx.x; i < 1024; i += 256) {
    int idx = base + i;
    if (idx < n2) s += deg[idx];
  }
  red[threadIdx.x] = s;
  __syncthreads();
  for (int off = 128; off > 0; off >>= 1) {
    if (threadIdx.x < off) red[threadIdx.x] += red[threadIdx.x + off];
    __syncthreads();
  }
  if (threadIdx.x == 0) bsums[blockIdx.x] = red[0];
}

// 256-thread LDS scan of block sums (nb <= 256)
__global__ void scan_top_par(int* __restrict__ bsums, int nb) {
  __shared__ int lds[2][256];
  int t = threadIdx.x;
  int v = (t < nb) ? bsums[t] : 0;
  lds[0][t] = v;
  __syncthreads();
  int cur = 0;
  for (int d2 = 1; d2 < 256; d2 <<= 1) {
    int val = lds[cur][t];
    if (t >= d2) val += lds[cur][t - d2];
    lds[cur ^ 1][t] = val;
    __syncthreads();
    cur ^= 1;
  }
  if (t < nb) bsums[t] = lds[cur][t] - v;  // exclusive
}

// rp is [2N+2]: rp1 = rp[0..N], rp2 = rp[N+1..2N+1] (shifted to avoid sentinel clash).
// fl/inv are [2N], unshifted.
__global__ void scan_final(const int* __restrict__ deg, const int* __restrict__ bsums,
                           int* __restrict__ rp, int* __restrict__ fill,
                           float* __restrict__ invdeg, int n2, int Nn, int E) {
  __shared__ int buf[2][256];
  int base = blockIdx.x * 1024;
  int v[4];
  int s = 0;
#pragma unroll
  for (int j = 0; j < 4; ++j) {
    int idx = base + threadIdx.x * 4 + j;
    v[j] = (idx < n2) ? deg[idx] : 0;
    s += v[j];
  }
  buf[0][threadIdx.x] = s;
  __syncthreads();
  int cur = 0;
  for (int d2 = 1; d2 < 256; d2 <<= 1) {
    int val = buf[cur][threadIdx.x];
    if (threadIdx.x >= d2) val += buf[cur][threadIdx.x - d2];
    buf[cur ^ 1][threadIdx.x] = val;
    __syncthreads();
    cur ^= 1;
  }
  int run = buf[cur][threadIdx.x] - s + bsums[blockIdx.x];
#pragma unroll
  for (int j = 0; j < 4; ++j) {
    int idx = base + threadIdx.x * 4 + j;
    if (idx < n2) {
      int isB = idx >= Nn;
      int off = isB ? E : 0;
      rp[idx + isB] = run - off;       // shift type-2 entries by one slot
      fill[idx] = run - off;
      int dv = v[j] < 1 ? 1 : v[j];
      invdeg[idx] = 1.0f / (float)dv;
      run += v[j];
    }
  }
  if (blockIdx.x == 0 && threadIdx.x == 0) {
    rp[Nn] = E;       // rp1 sentinel
    rp[n2 + 1] = E;   // rp2 sentinel
  }
}

__global__ void fill_csr2(const int* __restrict__ ei1, const int* __restrict__ ei2,
                          int* __restrict__ fl1, int* __restrict__ fl2,
                          int* __restrict__ col1, int* __restrict__ col2, int E) {
  int i = blockIdx.x * 256 + threadIdx.x;
  if (i < E) {
    int p = atomicAdd(&fl1[ei1[E + i]], 1);
    col1[p] = ei1[i];
  } else if (i < 2 * E) {
    int j = i - E;
    int p = atomicAdd(&fl2[ei2[E + j]], 1);
    col2[p] = ei2[j];
  }
}

// ------------- weight pack (both layers): B-fragment order, hi/lo split -------------
__global__ void wpack2(const float* __restrict__ W1n1, const float* __restrict__ W1n2,
                       const float* __restrict__ W1s1, const float* __restrict__ W1s2,
                       const float* __restrict__ W2n1, const float* __restrict__ W2n2,
                       const float* __restrict__ W2s1, const float* __restrict__ W2s2,
                       bf16x8* __restrict__ Wh1, bf16x8* __restrict__ Wl1,
                       bf16x8* __restrict__ Wh2, bf16x8* __restrict__ Wl2) {
  int bid = blockIdx.x;            // 0..47
  int layer = bid >= 24;
  int ct = bid - layer * 24;
  const float* Wn1 = layer ? W2n1 : W1n1;
  const float* Wn2 = layer ? W2n2 : W1n2;
  const float* Ws1 = layer ? W2s1 : W1s1;
  const float* Ws2 = layer ? W2s2 : W1s2;
  bf16x8* Wh = layer ? Wh2 : Wh1;
  bf16x8* Wl = layer ? Wl2 : Wl1;
  int ks = threadIdx.x >> 6;
  int l = threadIdx.x & 63;
  int col = (ct & 7) * 16 + (l & 15);
  int k0 = ks * 32 + (l >> 4) * 8;
  bf16x8 hv, lv;
#pragma unroll
  for (int j = 0; j < 8; ++j) {
    int k = k0 + j;
    float v;
    if (ct < 8)       v = Wn1[k * D + col];
    else if (ct < 16) v = Wn2[k * D + col];
    else              v = Ws1[k * D + col] + Ws2[k * D + col];
    ushort h = f2bf(v);
    float r = v - bf2f(h);
    hv[j] = (short)h;
    lv[j] = (short)f2bf(r);
  }
  int idx = (ct * 4 + ks) * 64 + l;
  Wh[idx] = hv;
  Wl[idx] = lv;
}

// ---------------- X pack into A-fragment order (hi/lo split) ----------------
__global__ void xpack(const float* __restrict__ X, bf16x8* __restrict__ Xh,
                      bf16x8* __restrict__ Xl, int M) {
  int g = blockIdx.x;
  int ks = threadIdx.x >> 6;
  int l = threadIdx.x & 63;
  int row = g * 16 + (l & 15);
  int c0 = ks * 32 + (l >> 4) * 8;
  bf16x8 hv, lv;
  if (row < M) {
    float4 a = *reinterpret_cast<const float4*>(X + (size_t)row * D + c0);
    float4 b = *reinterpret_cast<const float4*>(X + (size_t)row * D + c0 + 4);
    float xs[8] = {a.x, a.y, a.z, a.w, b.x, b.y, b.z, b.w};
#pragma unroll
    for (int j = 0; j < 8; ++j) {
      ushort h = f2bf(xs[j]);
      float r = xs[j] - bf2f(h);
      hv[j] = (short)h;
      lv[j] = (short)f2bf(r);
    }
  } else {
#pragma unroll
    for (int j = 0; j < 8; ++j) { hv[j] = 0; lv[j] = 0; }
  }
  int idx = (g * 4 + ks) * 64 + l;
  Xh[idx] = hv;
  Xl[idx] = lv;
}

// ------- MFMA GEMM: 32 rows/block, 8 waves, 3 col-tiles/wave (acc 24 AGPR) -------
__global__ __launch_bounds__(512) void gemm_mfma(
    const bf16x8* __restrict__ Xh, const bf16x8* __restrict__ Xl,
    const bf16x8* __restrict__ Wh, const bf16x8* __restrict__ Wl,
    ushort* __restrict__ Hn1b, ushort* __restrict__ Hn2b,
    ushort* __restrict__ Hsb, int M) {
  int w = __builtin_amdgcn_readfirstlane(threadIdx.x >> 6);  // 0..7
  int l = threadIdx.x & 63;
  int rb = blockIdx.x;   // 32-row tile

  f32x4 acc[2][3];
#pragma unroll
  for (int rt = 0; rt < 2; ++rt)
#pragma unroll
    for (int i = 0; i < 3; ++i)
      acc[rt][i] = (f32x4){0.f, 0.f, 0.f, 0.f};

#pragma unroll
  for (int ks = 0; ks < 4; ++ks) {
    bf16x8 Ah[2], Al[2];
#pragma unroll
    for (int rt = 0; rt < 2; ++rt) {
      int gi = ((rb * 2 + rt) * 4 + ks) * 64 + l;
      Ah[rt] = Xh[gi];
      Al[rt] = Xl[gi];
    }
#pragma unroll
    for (int i = 0; i < 3; ++i) {
      int ct = w + 8 * i;
      int wi = (ct * 4 + ks) * 64 + l;
      bf16x8 bh = Wh[wi];
      bf16x8 bl = Wl[wi];
#pragma unroll
      for (int rt = 0; rt < 2; ++rt) {
        acc[rt][i] = __builtin_amdgcn_mfma_f32_16x16x32_bf16(Ah[rt], bh, acc[rt][i], 0, 0, 0);
        acc[rt][i] = __builtin_amdgcn_mfma_f32_16x16x32_bf16(Ah[rt], bl, acc[rt][i], 0, 0, 0);
        acc[rt][i] = __builtin_amdgcn_mfma_f32_16x16x32_bf16(Al[rt], bh, acc[rt][i], 0, 0, 0);
      }
    }
  }

  int cq = l & 15;
  int rq = (l >> 4) * 4;
#pragma unroll
  for (int i = 0; i < 3; ++i) {
    int ct = w + 8 * i;  // wave-uniform
    ushort* dstbuf = (ct < 8) ? Hn1b : (ct < 16) ? Hn2b : Hsb;
    int cc = (ct & 7) * 16 + cq;
#pragma unroll
    for (int rt = 0; rt < 2; ++rt) {
      int R0 = rb * 32 + rt * 16 + rq;
#pragma unroll
      for (int r = 0; r < 4; ++r) {
        int R = R0 + r;
        if (R < M) dstbuf[(size_t)R * D + cc] = f2bf(acc[rt][i][r]);
      }
    }
  }
}

// ---- fused aggregation + BN partial stats ----
__global__ __launch_bounds__(256) void fused_agg(
    ushort* __restrict__ Hsb, const ushort* __restrict__ Hn1b,
    const ushort* __restrict__ Hn2b,
    const int* __restrict__ rp1, const int* __restrict__ col1,
    const float* __restrict__ inv1,
    const int* __restrict__ rp2, const int* __restrict__ col2,
    const float* __restrict__ inv2,
    float* __restrict__ part_s, float* __restrict__ part_q, int Nn) {
  __shared__ float lds_s[4][128];
  __shared__ float lds_q[4][128];
  int wv = threadIdx.x >> 6;
  int l = threadIdx.x & 63;
  int n = blockIdx.x * 4 + wv;
  int t2 = l * 2;
  float c0 = 0.f, c1 = 0.f;
  if (n < Nn) {
    int b1 = rp1[n], e1 = rp1[n + 1];
    int b2 = rp2[n], e2 = rp2[n + 1];
    float i1 = inv1[n], i2 = inv2[n];
    int len1 = e1 - b1, len2 = e2 - b2;
    int lmax = len1 > len2 ? len1 : len2;
    float pa = 0.f, pb = 0.f, qa = 0.f, qb = 0.f;
    for (int j0 = 0; j0 < lmax; j0 += 8) {
      int i1x[8], i2x[8];
      float m1[8], m2[8];
#pragma unroll
      for (int k = 0; k < 8; ++k) {
        int a = j0 + k;
        i1x[k] = (len1 > 0) ? col1[b1 + (a < len1 ? a : len1 - 1)] : 0;
        i2x[k] = (len2 > 0) ? col2[b2 + (a < len2 ? a : len2 - 1)] : 0;
        m1[k] = (a < len1) ? 1.f : 0.f;
        m2[k] = (a < len2) ? 1.f : 0.f;
      }
      uint v1[8], v2[8];
#pragma unroll
      for (int k = 0; k < 8; ++k) {
        v1[k] = *reinterpret_cast<const uint*>(Hn1b + (size_t)i1x[k] * D + t2);
        v2[k] = *reinterpret_cast<const uint*>(Hn2b + (size_t)i2x[k] * D + t2);
      }
#pragma unroll
      for (int k = 0; k < 8; ++k) {
        pa = fmaf(m1[k], bf2f((ushort)(v1[k] & 0xFFFF)), pa);
        pb = fmaf(m1[k], bf2f((ushort)(v1[k] >> 16)), pb);
        qa = fmaf(m2[k], bf2f((ushort)(v2[k] & 0xFFFF)), qa);
        qb = fmaf(m2[k], bf2f((ushort)(v2[k] >> 16)), qb);
      }
    }
    uint sv = *reinterpret_cast<const uint*>(Hsb + (size_t)n * D + t2);
    c0 = bf2f((ushort)(sv & 0xFFFF)) + pa * i1 + qa * i2;
    c1 = bf2f((ushort)(sv >> 16)) + pb * i1 + qb * i2;
    ushort h0 = f2bf(c0), h1 = f2bf(c1);
    *reinterpret_cast<uint*>(Hsb + (size_t)n * D + t2) = ((uint)h1 << 16) | (uint)h0;
    c0 = bf2f(h0);  // stats on stored (rounded) values: self-consistent BN
    c1 = bf2f(h1);
  }
  lds_s[wv][t2] = c0;
  lds_s[wv][t2 + 1] = c1;
  lds_q[wv][t2] = c0 * c0;
  lds_q[wv][t2 + 1] = c1 * c1;
  __syncthreads();
  if (threadIdx.x < 128) {
    int c = threadIdx.x;
    float s = lds_s[0][c] + lds_s[1][c] + lds_s[2][c] + lds_s[3][c];
    float q = lds_q[0][c] + lds_q[1][c] + lds_q[2][c] + lds_q[3][c];
    int slot = (blockIdx.x & 63) * 128 + c;
    atomicAdd(&part_s[slot], s);
    atomicAdd(&part_q[slot], q);
  }
}

// ---- finalize BN: partials -> per-column affine coef; re-zero partials ----
__global__ void bn_finalize(float* __restrict__ part_s, float* __restrict__ part_q,
                            const float* __restrict__ g, const float* __restrict__ b,
                            float* __restrict__ coef, float invM) {
  int c = threadIdx.x;
  if (c >= D) return;
  float s = 0.f, q = 0.f;
#pragma unroll 4
  for (int i = 0; i < 64; ++i) {
    s += part_s[i * 128 + c];
    part_s[i * 128 + c] = 0.f;
    q += part_q[i * 128 + c];
    part_q[i * 128 + c] = 0.f;
  }
  float mean = s * invM;
  float var = q * invM - mean * mean;
  float sc = rsqrtf(var + EPS) * g[c];
  coef[c] = sc;
  coef[D + c] = b[c] - mean * sc;
}

// ---- BN(affine)+LeakyReLU applied to Hsb; split-pack into A-fragment order ----
__global__ void bn_apply_pack(const ushort* __restrict__ Hsb, const float* __restrict__ coef,
                              bf16x8* __restrict__ Ah, bf16x8* __restrict__ Al, int M) {
  int g = blockIdx.x;
  int ks = threadIdx.x >> 6;
  int l = threadIdx.x & 63;
  int row = g * 16 + (l & 15);
  int c0 = ks * 32 + (l >> 4) * 8;
  bf16x8 hv, lv;
  if (row < M) {
    bf16x8 in = *reinterpret_cast<const bf16x8*>(Hsb + (size_t)row * D + c0);
#pragma unroll
    for (int j = 0; j < 8; ++j) {
      int c = c0 + j;
      float v = fmaf(bf2f((ushort)in[j]), coef[c], coef[D + c]);
      v = v > 0.f ? v : SLOPE * v;
      ushort h = f2bf(v);
      float r = v - bf2f(h);
      hv[j] = (short)h;
      lv[j] = (short)f2bf(r);
    }
  } else {
#pragma unroll
    for (int j = 0; j < 8; ++j) { hv[j] = 0; lv[j] = 0; }
  }
  int idx = (g * 4 + ks) * 64 + l;
  Ah[idx] = hv;
  Al[idx] = lv;
}

// ------- edge-label dots: gather bf16 rows, BN affine applied inline -------
__global__ void edge_dot_bn(const ushort* __restrict__ Hb, const float* __restrict__ coef,
                            const int* __restrict__ ea, const int* __restrict__ eb,
                            float* __restrict__ out, int EL) {
  int tt = blockIdx.x * 256 + threadIdx.x;
  int e = tt >> 4, l = tt & 15;
  if (e >= EL) return;
  int cb = l * 8;
  float4 sc0 = *reinterpret_cast<const float4*>(coef + cb);
  float4 sc1 = *reinterpret_cast<const float4*>(coef + cb + 4);
  float4 sh0 = *reinterpret_cast<const float4*>(coef + D + cb);
  float4 sh1 = *reinterpret_cast<const float4*>(coef + D + cb + 4);
  float sc[8] = {sc0.x, sc0.y, sc0.z, sc0.w, sc1.x, sc1.y, sc1.z, sc1.w};
  float sh[8] = {sh0.x, sh0.y, sh0.z, sh0.w, sh1.x, sh1.y, sh1.z, sh1.w};
  bf16x8 av = *reinterpret_cast<const bf16x8*>(Hb + (size_t)ea[e] * D + cb);
  bf16x8 bv = *reinterpret_cast<const bf16x8*>(Hb + (size_t)eb[e] * D + cb);
  float d = 0.f;
#pragma unroll
  for (int j = 0; j < 8; ++j) {
    float fa = fmaf(bf2f((ushort)av[j]), sc[j], sh[j]);
    float fb = fmaf(bf2f((ushort)bv[j]), sc[j], sh[j]);
    d = fmaf(fa, fb, d);
  }
  d += __shfl_xor(d, 1);
  d += __shfl_xor(d, 2);
  d += __shfl_xor(d, 4);
  d += __shfl_xor(d, 8);
  if (l == 0) out[e] = d;
}

// ---------------- launch ----------------
extern "C" void kernel_launch(void* const* d_in, const int* in_sizes, int n_in,
                              void* d_out, int out_size, void* d_ws, size_t ws_size,
                              hipStream_t stream) {
  const float* x    = (const float*)d_in[0];
  const int* ei1    = (const int*)d_in[1];
  const int* ei2    = (const int*)d_in[2];
  const int* eli    = (const int*)d_in[3];
  const float* W1n1 = (const float*)d_in[4];
  const float* W1s1 = (const float*)d_in[5];
  const float* W1n2 = (const float*)d_in[6];
  const float* W1s2 = (const float*)d_in[7];
  const float* W2n1 = (const float*)d_in[8];
  const float* W2s1 = (const float*)d_in[9];
  const float* W2n2 = (const float*)d_in[10];
  const float* W2s2 = (const float*)d_in[11];
  const float* g1   = (const float*)d_in[12];
  const float* b1   = (const float*)d_in[13];
  const float* g2   = (const float*)d_in[14];
  const float* b2   = (const float*)d_in[15];
  float* out = (float*)d_out;

  const int N = NN, E = NE;
  const int EL = in_sizes[3] / 2;
  const int RB = (N + 31) / 32;       // 32-row gemm blocks (3125)
  const int G = RB * 2;               // 16-row A-fragment tiles (6250)
  const int N2 = 2 * N;

  char* w = (char*)d_ws;
  // zeroed region (one memset): deg[2N], part_s, part_q
  int* deg = (int*)w; w += (size_t)N2 * 4;
  float* part_s = (float*)w; w += (size_t)64 * 128 * 4;
  float* part_q = (float*)w; w += (size_t)64 * 128 * 4;
  size_t zbytes = (size_t)(N2 + 2 * 64 * 128) * 4;

  bf16x8* Xh = (bf16x8*)w; w += (size_t)G * 4 * 64 * 16;
  bf16x8* Xl = (bf16x8*)w; w += (size_t)G * 4 * 64 * 16;
  ushort* Hn1b = (ushort*)w; w += (size_t)N * D * 2;
  ushort* Hn2b = (ushort*)w; w += (size_t)N * D * 2;
  ushort* Hsb  = (ushort*)w; w += (size_t)N * D * 2;
  bf16x8* Wh1 = (bf16x8*)w; w += (size_t)24 * 4 * 64 * 16;
  bf16x8* Wl1 = (bf16x8*)w; w += (size_t)24 * 4 * 64 * 16;
  bf16x8* Wh2 = (bf16x8*)w; w += (size_t)24 * 4 * 64 * 16;
  bf16x8* Wl2 = (bf16x8*)w; w += (size_t)24 * 4 * 64 * 16;
  int* rp   = (int*)w; w += (size_t)(N2 + 2) * 4;   // rp1 = rp[0..N], rp2 = rp[N+1..2N+1]
  int* fl   = (int*)w; w += (size_t)N2 * 4;         // fl1 = fl, fl2 = fl + N
  int* col1 = (int*)w; w += (size_t)E * 4;
  int* col2 = (int*)w; w += (size_t)E * 4;
  float* inv = (float*)w; w += (size_t)N2 * 4;      // inv1 = inv, inv2 = inv + N
  int* bsums = (int*)w; w += 256 * 4;
  float* coef1 = (float*)w; w += 2 * D * 4;
  float* coef2 = (float*)w; w += 2 * D * 4;

  hipMemsetAsync(deg, 0, zbytes, stream);

  int e2b = (2 * E + 255) / 256;
  count_deg2<<<e2b, 256, 0, stream>>>(ei1, ei2, E, deg, N);
  int nb = (N2 + 1023) / 1024;  // 196
  scan_block_sums<<<nb, 256, 0, stream>>>(deg, bsums, N2);
  scan_top_par<<<1, 256, 0, stream>>>(bsums, nb);
  scan_final<<<nb, 256, 0, stream>>>(deg, bsums, rp, fl, inv, N2, N, E);
  fill_csr2<<<e2b, 256, 0, stream>>>(ei1, ei2, fl, fl + N, col1, col2, E);

  wpack2<<<48, 256, 0, stream>>>(W1n1, W1n2, W1s1, W1s2, W2n1, W2n2, W2s1, W2s2,
                                 Wh1, Wl1, Wh2, Wl2);
  xpack<<<G, 256, 0, stream>>>(x, Xh, Xl, N);

  int agb = (N + 3) / 4;
  int* rp2p = rp + N + 1;

  // ---- Layer 1 ----
  gemm_mfma<<<RB, 512, 0, stream>>>(Xh, Xl, Wh1, Wl1, Hn1b, Hn2b, Hsb, N);
  fused_agg<<<agb, 256, 0, stream>>>(Hsb, Hn1b, Hn2b, rp, col1, inv, rp2p, col2, inv + N,
                                     part_s, part_q, N);
  bn_finalize<<<1, 128, 0, stream>>>(part_s, part_q, g1, b1, coef1, 1.0f / N);
  bn_apply_pack<<<G, 256, 0, stream>>>(Hsb, coef1, Xh, Xl, N);  // overwrite X packs

  // ---- Layer 2 ----
  gemm_mfma<<<RB, 512, 0, stream>>>(Xh, Xl, Wh2, Wl2, Hn1b, Hn2b, Hsb, N);
  fused_agg<<<agb, 256, 0, stream>>>(Hsb, Hn1b, Hn2b, rp, col1, inv, rp2p, col2, inv + N,
                                     part_s, part_q, N);
  bn_finalize<<<1, 128, 0, stream>>>(part_s, part_q, g2, b2, coef2, 1.0f / N);

  // ---- edge-label dots (bf16 gathers, BN affine fused) ----
  int db = (int)(((size_t)EL * 16 + 255) / 256);
  edge_dot_bn<<<db, 256, 0, stream>>>(Hsb, coef2, eli, eli + EL, out, EL);
}

// Round 9
// 435.275 us; speedup vs baseline: 2.5193x; 1.2705x over previous
//
#include <hip/hip_runtime.h>

#define NN 100000
#define NE 500000
#define D 128
#define EPS 1e-5f
#define SLOPE 0.01f
#define COLCAP (2 * NE + 6 * NN + 64)   // worst-case combined padded col entries

typedef short bf16x8 __attribute__((ext_vector_type(8)));
typedef float f32x4 __attribute__((ext_vector_type(4)));

__device__ __forceinline__ ushort f2bf(float x) {
  uint u = __float_as_uint(x);
  u += 0x7FFF + ((u >> 16) & 1);
  return (ushort)(u >> 16);
}
__device__ __forceinline__ float bf2f(ushort h) {
  return __uint_as_float(((uint)h) << 16);
}

// ---------------- CSR build: count both edge types in one kernel ----------------
// deg is a combined [2N] array: deg1 = deg, deg2 = deg + N.
__global__ void count_deg2(const int* __restrict__ ei1, const int* __restrict__ ei2,
                           int E, int* __restrict__ deg, int Nn) {
  int i = blockIdx.x * 256 + threadIdx.x;
  if (i < E) atomicAdd(&deg[ei1[E + i]], 1);
  else if (i < 2 * E) atomicAdd(&deg[Nn + ei2[E + (i - E)]], 1);
}

// ---- combined multi-block exclusive scan over PADDED deg[2N] (pad to multiple of 4) ----
__global__ void scan_block_sums(const int* __restrict__ deg, int* __restrict__ bsums, int n2) {
  __shared__ int red[256];
  int base = blockIdx.x * 1024;
  int s = 0;
  for (int i = threadIdx.x; i < 1024; i += 256) {
    int idx = base + i;
    if (idx < n2) s += (deg[idx] + 3) & ~3;
  }
  red[threadIdx.x] = s;
  __syncthreads();
  for (int off = 128; off > 0; off >>= 1) {
    if (threadIdx.x < off) red[threadIdx.x] += red[threadIdx.x + off];
    __syncthreads();
  }
  if (threadIdx.x == 0) bsums[blockIdx.x] = red[0];
}

// 256-thread LDS scan of block sums (nb <= 256)
__global__ void scan_top_par(int* __restrict__ bsums, int nb) {
  __shared__ int lds[2][256];
  int t = threadIdx.x;
  int v = (t < nb) ? bsums[t] : 0;
  lds[0][t] = v;
  __syncthreads();
  int cur = 0;
  for (int d2 = 1; d2 < 256; d2 <<= 1) {
    int val = lds[cur][t];
    if (t >= d2) val += lds[cur][t - d2];
    lds[cur ^ 1][t] = val;
    __syncthreads();
    cur ^= 1;
  }
  if (t < nb) bsums[t] = lds[cur][t] - v;  // exclusive
}

// rp is [2N+2]: rp1 = rp[0..N], rp2 = rp[N+1..2N+1]; values are COMBINED padded offsets.
// fl is [2N] (combined offsets, unshifted). inv from real deg.
__global__ void scan_final(const int* __restrict__ deg, const int* __restrict__ bsums,
                           int* __restrict__ rp, int* __restrict__ fill,
                           float* __restrict__ invdeg, int n2, int Nn) {
  __shared__ int buf[2][256];
  int base = blockIdx.x * 1024;
  int v[4], p[4];
  int s = 0;
#pragma unroll
  for (int j = 0; j < 4; ++j) {
    int idx = base + threadIdx.x * 4 + j;
    v[j] = (idx < n2) ? deg[idx] : 0;
    p[j] = (v[j] + 3) & ~3;
    s += p[j];
  }
  buf[0][threadIdx.x] = s;
  __syncthreads();
  int cur = 0;
  for (int d2 = 1; d2 < 256; d2 <<= 1) {
    int val = buf[cur][threadIdx.x];
    if (threadIdx.x >= d2) val += buf[cur][threadIdx.x - d2];
    buf[cur ^ 1][threadIdx.x] = val;
    __syncthreads();
    cur ^= 1;
  }
  int run = buf[cur][threadIdx.x] - s + bsums[blockIdx.x];
#pragma unroll
  for (int j = 0; j < 4; ++j) {
    int idx = base + threadIdx.x * 4 + j;
    if (idx < n2) {
      int isB = idx >= Nn;
      rp[idx + isB] = run;          // combined padded offset (no subtraction)
      fill[idx] = run;
      int dv = v[j] < 1 ? 1 : v[j];
      invdeg[idx] = 1.0f / (float)dv;
      run += p[j];
      if (idx == Nn - 1) rp[Nn] = run;        // rp1 sentinel = Ppad1
      if (idx == n2 - 1) rp[n2 + 1] = run;    // rp2 sentinel = Ppad1+Ppad2
    }
  }
}

// pre-fill colC with dummy index N; zero the dummy rows of Hn1b/Hn2b
__global__ void fill_pad(int* __restrict__ colC, ushort* __restrict__ Hn1b,
                         ushort* __restrict__ Hn2b, int cap, int Nn) {
  int i = blockIdx.x * 256 + threadIdx.x;
  if (i < cap) colC[i] = Nn;
  if (blockIdx.x == 0 && threadIdx.x < D) {
    Hn1b[(size_t)Nn * D + threadIdx.x] = 0;
    Hn2b[(size_t)Nn * D + threadIdx.x] = 0;
  }
}

// fill combined col array; fl1 = fl, fl2 = fl + N (combined offsets)
__global__ void fill_csr2(const int* __restrict__ ei1, const int* __restrict__ ei2,
                          int* __restrict__ fl, int* __restrict__ colC, int E, int Nn) {
  int i = blockIdx.x * 256 + threadIdx.x;
  if (i < E) {
    int p = atomicAdd(&fl[ei1[E + i]], 1);
    colC[p] = ei1[i];
  } else if (i < 2 * E) {
    int j = i - E;
    int p = atomicAdd(&fl[Nn + ei2[E + j]], 1);
    colC[p] = ei2[j];
  }
}

// ------------- weight pack (both layers): B-fragment order, hi/lo split -------------
__global__ void wpack2(const float* __restrict__ W1n1, const float* __restrict__ W1n2,
                       const float* __restrict__ W1s1, const float* __restrict__ W1s2,
                       const float* __restrict__ W2n1, const float* __restrict__ W2n2,
                       const float* __restrict__ W2s1, const float* __restrict__ W2s2,
                       bf16x8* __restrict__ Wh1, bf16x8* __restrict__ Wl1,
                       bf16x8* __restrict__ Wh2, bf16x8* __restrict__ Wl2) {
  int bid = blockIdx.x;            // 0..47
  int layer = bid >= 24;
  int ct = bid - layer * 24;
  const float* Wn1 = layer ? W2n1 : W1n1;
  const float* Wn2 = layer ? W2n2 : W1n2;
  const float* Ws1 = layer ? W2s1 : W1s1;
  const float* Ws2 = layer ? W2s2 : W1s2;
  bf16x8* Wh = layer ? Wh2 : Wh1;
  bf16x8* Wl = layer ? Wl2 : Wl1;
  int ks = threadIdx.x >> 6;
  int l = threadIdx.x & 63;
  int col = (ct & 7) * 16 + (l & 15);
  int k0 = ks * 32 + (l >> 4) * 8;
  bf16x8 hv, lv;
#pragma unroll
  for (int j = 0; j < 8; ++j) {
    int k = k0 + j;
    float v;
    if (ct < 8)       v = Wn1[k * D + col];
    else if (ct < 16) v = Wn2[k * D + col];
    else              v = Ws1[k * D + col] + Ws2[k * D + col];
    ushort h = f2bf(v);
    float r = v - bf2f(h);
    hv[j] = (short)h;
    lv[j] = (short)f2bf(r);
  }
  int idx = (ct * 4 + ks) * 64 + l;
  Wh[idx] = hv;
  Wl[idx] = lv;
}

// ---------------- X pack into A-fragment order (hi/lo split) ----------------
__global__ void xpack(const float* __restrict__ X, bf16x8* __restrict__ Xh,
                      bf16x8* __restrict__ Xl, int M) {
  int g = blockIdx.x;
  int ks = threadIdx.x >> 6;
  int l = threadIdx.x & 63;
  int row = g * 16 + (l & 15);
  int c0 = ks * 32 + (l >> 4) * 8;
  bf16x8 hv, lv;
  if (row < M) {
    float4 a = *reinterpret_cast<const float4*>(X + (size_t)row * D + c0);
    float4 b = *reinterpret_cast<const float4*>(X + (size_t)row * D + c0 + 4);
    float xs[8] = {a.x, a.y, a.z, a.w, b.x, b.y, b.z, b.w};
#pragma unroll
    for (int j = 0; j < 8; ++j) {
      ushort h = f2bf(xs[j]);
      float r = xs[j] - bf2f(h);
      hv[j] = (short)h;
      lv[j] = (short)f2bf(r);
    }
  } else {
#pragma unroll
    for (int j = 0; j < 8; ++j) { hv[j] = 0; lv[j] = 0; }
  }
  int idx = (g * 4 + ks) * 64 + l;
  Xh[idx] = hv;
  Xl[idx] = lv;
}

// ------- MFMA GEMM: 32 rows/block, 8 waves, 3 col-tiles/wave (acc 24 AGPR) -------
__global__ __launch_bounds__(512) void gemm_mfma(
    const bf16x8* __restrict__ Xh, const bf16x8* __restrict__ Xl,
    const bf16x8* __restrict__ Wh, const bf16x8* __restrict__ Wl,
    ushort* __restrict__ Hn1b, ushort* __restrict__ Hn2b,
    ushort* __restrict__ Hsb, int M) {
  int w = __builtin_amdgcn_readfirstlane(threadIdx.x >> 6);  // 0..7
  int l = threadIdx.x & 63;
  int rb = blockIdx.x;   // 32-row tile

  f32x4 acc[2][3];
#pragma unroll
  for (int rt = 0; rt < 2; ++rt)
#pragma unroll
    for (int i = 0; i < 3; ++i)
      acc[rt][i] = (f32x4){0.f, 0.f, 0.f, 0.f};

#pragma unroll
  for (int ks = 0; ks < 4; ++ks) {
    bf16x8 Ah[2], Al[2];
#pragma unroll
    for (int rt = 0; rt < 2; ++rt) {
      int gi = ((rb * 2 + rt) * 4 + ks) * 64 + l;
      Ah[rt] = Xh[gi];
      Al[rt] = Xl[gi];
    }
#pragma unroll
    for (int i = 0; i < 3; ++i) {
      int ct = w + 8 * i;
      int wi = (ct * 4 + ks) * 64 + l;
      bf16x8 bh = Wh[wi];
      bf16x8 bl = Wl[wi];
#pragma unroll
      for (int rt = 0; rt < 2; ++rt) {
        acc[rt][i] = __builtin_amdgcn_mfma_f32_16x16x32_bf16(Ah[rt], bh, acc[rt][i], 0, 0, 0);
        acc[rt][i] = __builtin_amdgcn_mfma_f32_16x16x32_bf16(Ah[rt], bl, acc[rt][i], 0, 0, 0);
        acc[rt][i] = __builtin_amdgcn_mfma_f32_16x16x32_bf16(Al[rt], bh, acc[rt][i], 0, 0, 0);
      }
    }
  }

  int cq = l & 15;
  int rq = (l >> 4) * 4;
#pragma unroll
  for (int i = 0; i < 3; ++i) {
    int ct = w + 8 * i;  // wave-uniform
    ushort* dstbuf = (ct < 8) ? Hn1b : (ct < 16) ? Hn2b : Hsb;
    int cc = (ct & 7) * 16 + cq;
#pragma unroll
    for (int rt = 0; rt < 2; ++rt) {
      int R0 = rb * 32 + rt * 16 + rq;
#pragma unroll
      for (int r = 0; r < 4; ++r) {
        int R = R0 + r;
        if (R < M) dstbuf[(size_t)R * D + cc] = f2bf(acc[rt][i][r]);
      }
    }
  }
}

// ---- fused aggregation (padded CSR: no masks/clamps) + BN partial stats ----
__global__ __launch_bounds__(256) void fused_agg(
    ushort* __restrict__ Hsb, const ushort* __restrict__ Hn1b,
    const ushort* __restrict__ Hn2b,
    const int* __restrict__ rp1, const int* __restrict__ rp2,
    const int* __restrict__ colC,
    const float* __restrict__ inv1, const float* __restrict__ inv2,
    float* __restrict__ part_s, float* __restrict__ part_q, int Nn) {
  __shared__ float lds_s[4][128];
  __shared__ float lds_q[4][128];
  int wv = threadIdx.x >> 6;
  int l = threadIdx.x & 63;
  int n = blockIdx.x * 4 + wv;
  int t2 = l * 2;
  float c0 = 0.f, c1 = 0.f;
  if (n < Nn) {
    int b1 = rp1[n], e1 = rp1[n + 1];
    int b2 = rp2[n], e2 = rp2[n + 1];
    float i1 = inv1[n], i2 = inv2[n];
    int pd1 = e1 - b1, pd2 = e2 - b2;       // multiples of 4
    int lmax = pd1 > pd2 ? pd1 : pd2;
    float pa = 0.f, pb = 0.f, qa = 0.f, qb = 0.f;
    for (int a = 0; a < lmax; a += 4) {
      int4 cA = (a < pd1) ? *reinterpret_cast<const int4*>(colC + b1 + a)
                          : make_int4(Nn, Nn, Nn, Nn);
      int4 cB = (a < pd2) ? *reinterpret_cast<const int4*>(colC + b2 + a)
                          : make_int4(Nn, Nn, Nn, Nn);
      uint v10 = *reinterpret_cast<const uint*>(Hn1b + (size_t)cA.x * D + t2);
      uint v11 = *reinterpret_cast<const uint*>(Hn1b + (size_t)cA.y * D + t2);
      uint v12 = *reinterpret_cast<const uint*>(Hn1b + (size_t)cA.z * D + t2);
      uint v13 = *reinterpret_cast<const uint*>(Hn1b + (size_t)cA.w * D + t2);
      uint v20 = *reinterpret_cast<const uint*>(Hn2b + (size_t)cB.x * D + t2);
      uint v21 = *reinterpret_cast<const uint*>(Hn2b + (size_t)cB.y * D + t2);
      uint v22 = *reinterpret_cast<const uint*>(Hn2b + (size_t)cB.z * D + t2);
      uint v23 = *reinterpret_cast<const uint*>(Hn2b + (size_t)cB.w * D + t2);
      pa += (bf2f((ushort)(v10 & 0xFFFF)) + bf2f((ushort)(v11 & 0xFFFF))) +
            (bf2f((ushort)(v12 & 0xFFFF)) + bf2f((ushort)(v13 & 0xFFFF)));
      pb += (bf2f((ushort)(v10 >> 16)) + bf2f((ushort)(v11 >> 16))) +
            (bf2f((ushort)(v12 >> 16)) + bf2f((ushort)(v13 >> 16)));
      qa += (bf2f((ushort)(v20 & 0xFFFF)) + bf2f((ushort)(v21 & 0xFFFF))) +
            (bf2f((ushort)(v22 & 0xFFFF)) + bf2f((ushort)(v23 & 0xFFFF)));
      qb += (bf2f((ushort)(v20 >> 16)) + bf2f((ushort)(v21 >> 16))) +
            (bf2f((ushort)(v22 >> 16)) + bf2f((ushort)(v23 >> 16)));
    }
    uint sv = *reinterpret_cast<const uint*>(Hsb + (size_t)n * D + t2);
    c0 = bf2f((ushort)(sv & 0xFFFF)) + pa * i1 + qa * i2;
    c1 = bf2f((ushort)(sv >> 16)) + pb * i1 + qb * i2;
    ushort h0 = f2bf(c0), h1 = f2bf(c1);
    *reinterpret_cast<uint*>(Hsb + (size_t)n * D + t2) = ((uint)h1 << 16) | (uint)h0;
    c0 = bf2f(h0);  // stats on stored (rounded) values: self-consistent BN
    c1 = bf2f(h1);
  }
  lds_s[wv][t2] = c0;
  lds_s[wv][t2 + 1] = c1;
  lds_q[wv][t2] = c0 * c0;
  lds_q[wv][t2 + 1] = c1 * c1;
  __syncthreads();
  if (threadIdx.x < 128) {
    int c = threadIdx.x;
    float s = lds_s[0][c] + lds_s[1][c] + lds_s[2][c] + lds_s[3][c];
    float q = lds_q[0][c] + lds_q[1][c] + lds_q[2][c] + lds_q[3][c];
    int slot = (blockIdx.x & 63) * 128 + c;
    atomicAdd(&part_s[slot], s);
    atomicAdd(&part_q[slot], q);
  }
}

// ---- finalize BN: partials -> per-column affine coef; re-zero partials ----
__global__ void bn_finalize(float* __restrict__ part_s, float* __restrict__ part_q,
                            const float* __restrict__ g, const float* __restrict__ b,
                            float* __restrict__ coef, float invM) {
  int c = threadIdx.x;
  if (c >= D) return;
  float s = 0.f, q = 0.f;
#pragma unroll 4
  for (int i = 0; i < 64; ++i) {
    s += part_s[i * 128 + c];
    part_s[i * 128 + c] = 0.f;
    q += part_q[i * 128 + c];
    part_q[i * 128 + c] = 0.f;
  }
  float mean = s * invM;
  float var = q * invM - mean * mean;
  float sc = rsqrtf(var + EPS) * g[c];
  coef[c] = sc;
  coef[D + c] = b[c] - mean * sc;
}

// ---- BN(affine)+LeakyReLU applied to Hsb; split-pack into A-fragment order ----
__global__ void bn_apply_pack(const ushort* __restrict__ Hsb, const float* __restrict__ coef,
                              bf16x8* __restrict__ Ah, bf16x8* __restrict__ Al, int M) {
  int g = blockIdx.x;
  int ks = threadIdx.x >> 6;
  int l = threadIdx.x & 63;
  int row = g * 16 + (l & 15);
  int c0 = ks * 32 + (l >> 4) * 8;
  bf16x8 hv, lv;
  if (row < M) {
    bf16x8 in = *reinterpret_cast<const bf16x8*>(Hsb + (size_t)row * D + c0);
#pragma unroll
    for (int j = 0; j < 8; ++j) {
      int c = c0 + j;
      float v = fmaf(bf2f((ushort)in[j]), coef[c], coef[D + c]);
      v = v > 0.f ? v : SLOPE * v;
      ushort h = f2bf(v);
      float r = v - bf2f(h);
      hv[j] = (short)h;
      lv[j] = (short)f2bf(r);
    }
  } else {
#pragma unroll
    for (int j = 0; j < 8; ++j) { hv[j] = 0; lv[j] = 0; }
  }
  int idx = (g * 4 + ks) * 64 + l;
  Ah[idx] = hv;
  Al[idx] = lv;
}

// ------- edge-label dots: gather bf16 rows, BN affine applied inline -------
__global__ void edge_dot_bn(const ushort* __restrict__ Hb, const float* __restrict__ coef,
                            const int* __restrict__ ea, const int* __restrict__ eb,
                            float* __restrict__ out, int EL) {
  int tt = blockIdx.x * 256 + threadIdx.x;
  int e = tt >> 4, l = tt & 15;
  if (e >= EL) return;
  int cb = l * 8;
  float4 sc0 = *reinterpret_cast<const float4*>(coef + cb);
  float4 sc1 = *reinterpret_cast<const float4*>(coef + cb + 4);
  float4 sh0 = *reinterpret_cast<const float4*>(coef + D + cb);
  float4 sh1 = *reinterpret_cast<const float4*>(coef + D + cb + 4);
  float sc[8] = {sc0.x, sc0.y, sc0.z, sc0.w, sc1.x, sc1.y, sc1.z, sc1.w};
  float sh[8] = {sh0.x, sh0.y, sh0.z, sh0.w, sh1.x, sh1.y, sh1.z, sh1.w};
  bf16x8 av = *reinterpret_cast<const bf16x8*>(Hb + (size_t)ea[e] * D + cb);
  bf16x8 bv = *reinterpret_cast<const bf16x8*>(Hb + (size_t)eb[e] * D + cb);
  float d = 0.f;
#pragma unroll
  for (int j = 0; j < 8; ++j) {
    float fa = fmaf(bf2f((ushort)av[j]), sc[j], sh[j]);
    float fb = fmaf(bf2f((ushort)bv[j]), sc[j], sh[j]);
    d = fmaf(fa, fb, d);
  }
  d += __shfl_xor(d, 1);
  d += __shfl_xor(d, 2);
  d += __shfl_xor(d, 4);
  d += __shfl_xor(d, 8);
  if (l == 0) out[e] = d;
}

// ---------------- launch ----------------
extern "C" void kernel_launch(void* const* d_in, const int* in_sizes, int n_in,
                              void* d_out, int out_size, void* d_ws, size_t ws_size,
                              hipStream_t stream) {
  const float* x    = (const float*)d_in[0];
  const int* ei1    = (const int*)d_in[1];
  const int* ei2    = (const int*)d_in[2];
  const int* eli    = (const int*)d_in[3];
  const float* W1n1 = (const float*)d_in[4];
  const float* W1s1 = (const float*)d_in[5];
  const float* W1n2 = (const float*)d_in[6];
  const float* W1s2 = (const float*)d_in[7];
  const float* W2n1 = (const float*)d_in[8];
  const float* W2s1 = (const float*)d_in[9];
  const float* W2n2 = (const float*)d_in[10];
  const float* W2s2 = (const float*)d_in[11];
  const float* g1   = (const float*)d_in[12];
  const float* b1   = (const float*)d_in[13];
  const float* g2   = (const float*)d_in[14];
  const float* b2   = (const float*)d_in[15];
  float* out = (float*)d_out;

  const int N = NN, E = NE;
  const int EL = in_sizes[3] / 2;
  const int RB = (N + 31) / 32;       // 32-row gemm blocks (3125)
  const int G = RB * 2;               // 16-row A-fragment tiles (6250)
  const int N2 = 2 * N;

  char* w = (char*)d_ws;
  // zeroed region (one memset): deg[2N], part_s, part_q
  int* deg = (int*)w; w += (size_t)N2 * 4;
  float* part_s = (float*)w; w += (size_t)64 * 128 * 4;
  float* part_q = (float*)w; w += (size_t)64 * 128 * 4;
  size_t zbytes = (size_t)(N2 + 2 * 64 * 128) * 4;

  bf16x8* Xh = (bf16x8*)w; w += (size_t)G * 4 * 64 * 16;
  bf16x8* Xl = (bf16x8*)w; w += (size_t)G * 4 * 64 * 16;
  ushort* Hn1b = (ushort*)w; w += (size_t)(N + 1) * D * 2;   // +1 dummy zero row
  ushort* Hn2b = (ushort*)w; w += (size_t)(N + 1) * D * 2;   // +1 dummy zero row
  ushort* Hsb  = (ushort*)w; w += (size_t)N * D * 2;
  bf16x8* Wh1 = (bf16x8*)w; w += (size_t)24 * 4 * 64 * 16;
  bf16x8* Wl1 = (bf16x8*)w; w += (size_t)24 * 4 * 64 * 16;
  bf16x8* Wh2 = (bf16x8*)w; w += (size_t)24 * 4 * 64 * 16;
  bf16x8* Wl2 = (bf16x8*)w; w += (size_t)24 * 4 * 64 * 16;
  int* rp   = (int*)w; w += (size_t)(N2 + 2) * 4;   // rp1 = rp[0..N], rp2 = rp[N+1..2N+1]
  int* fl   = (int*)w; w += (size_t)N2 * 4;         // combined fill ptrs
  int* colC = (int*)w; w += (size_t)COLCAP * 4;     // combined padded col array
  float* inv = (float*)w; w += (size_t)N2 * 4;      // inv1 = inv, inv2 = inv + N
  int* bsums = (int*)w; w += 256 * 4;
  float* coef1 = (float*)w; w += 2 * D * 4;
  float* coef2 = (float*)w; w += 2 * D * 4;

  hipMemsetAsync(deg, 0, zbytes, stream);

  int e2b = (2 * E + 255) / 256;
  count_deg2<<<e2b, 256, 0, stream>>>(ei1, ei2, E, deg, N);
  int nb = (N2 + 1023) / 1024;  // 196
  scan_block_sums<<<nb, 256, 0, stream>>>(deg, bsums, N2);
  scan_top_par<<<1, 256, 0, stream>>>(bsums, nb);
  scan_final<<<nb, 256, 0, stream>>>(deg, bsums, rp, fl, inv, N2, N);
  fill_pad<<<(COLCAP + 255) / 256, 256, 0, stream>>>(colC, Hn1b, Hn2b, COLCAP, N);
  fill_csr2<<<e2b, 256, 0, stream>>>(ei1, ei2, fl, colC, E, N);

  wpack2<<<48, 256, 0, stream>>>(W1n1, W1n2, W1s1, W1s2, W2n1, W2n2, W2s1, W2s2,
                                 Wh1, Wl1, Wh2, Wl2);
  xpack<<<G, 256, 0, stream>>>(x, Xh, Xl, N);

  int agb = (N + 3) / 4;
  int* rp2p = rp + N + 1;

  // ---- Layer 1 ----
  gemm_mfma<<<RB, 512, 0, stream>>>(Xh, Xl, Wh1, Wl1, Hn1b, Hn2b, Hsb, N);
  fused_agg<<<agb, 256, 0, stream>>>(Hsb, Hn1b, Hn2b, rp, rp2p, colC, inv, inv + N,
                                     part_s, part_q, N);
  bn_finalize<<<1, 128, 0, stream>>>(part_s, part_q, g1, b1, coef1, 1.0f / N);
  bn_apply_pack<<<G, 256, 0, stream>>>(Hsb, coef1, Xh, Xl, N);  // overwrite X packs

  // ---- Layer 2 ----
  gemm_mfma<<<RB, 512, 0, stream>>>(Xh, Xl, Wh2, Wl2, Hn1b, Hn2b, Hsb, N);
  fused_agg<<<agb, 256, 0, stream>>>(Hsb, Hn1b, Hn2b, rp, rp2p, colC, inv, inv + N,
                                     part_s, part_q, N);
  bn_finalize<<<1, 128, 0, stream>>>(part_s, part_q, g2, b2, coef2, 1.0f / N);

  // ---- edge-label dots (bf16 gathers, BN affine fused) ----
  int db = (int)(((size_t)EL * 16 + 255) / 256);
  edge_dot_bn<<<db, 256, 0, stream>>>(Hsb, coef2, eli, eli + EL, out, EL);
}

// Round 10
// 371.691 us; speedup vs baseline: 2.9503x; 1.1711x over previous
//
#include <hip/hip_runtime.h>

#define NN 100000
#define NE 500000
#define D 128
#define EPS 1e-5f
#define SLOPE 0.01f
#define COLCAP (2 * NE + 6 * NN + 64)   // worst-case combined padded col entries

typedef short bf16x8 __attribute__((ext_vector_type(8)));
typedef float f32x4 __attribute__((ext_vector_type(4)));

__device__ __forceinline__ ushort f2bf(float x) {
  uint u = __float_as_uint(x);
  u += 0x7FFF + ((u >> 16) & 1);
  return (ushort)(u >> 16);
}
__device__ __forceinline__ float bf2f(ushort h) {
  return __uint_as_float(((uint)h) << 16);
}

// ---- CSR count pass: histogram via atomics, storing each edge's rank (atomic return) ----
// deg is combined [2N]: deg1 = deg, deg2 = deg + N. rank is combined [2E].
__global__ void count_rank(const int* __restrict__ ei1, const int* __restrict__ ei2,
                           int E, int* __restrict__ deg, int* __restrict__ rank, int Nn) {
  int i = blockIdx.x * 256 + threadIdx.x;
  if (i < E) {
    rank[i] = atomicAdd(&deg[ei1[E + i]], 1);
  } else if (i < 2 * E) {
    int j = i - E;
    rank[i] = atomicAdd(&deg[Nn + ei2[E + j]], 1);
  }
}

// ---- combined multi-block exclusive scan over PADDED deg[2N] (pad to multiple of 4) ----
__global__ void scan_block_sums(const int* __restrict__ deg, int* __restrict__ bsums, int n2) {
  __shared__ int red[256];
  int base = blockIdx.x * 1024;
  int s = 0;
  for (int i = threadIdx.x; i < 1024; i += 256) {
    int idx = base + i;
    if (idx < n2) s += (deg[idx] + 3) & ~3;
  }
  red[threadIdx.x] = s;
  __syncthreads();
  for (int off = 128; off > 0; off >>= 1) {
    if (threadIdx.x < off) red[threadIdx.x] += red[threadIdx.x + off];
    __syncthreads();
  }
  if (threadIdx.x == 0) bsums[blockIdx.x] = red[0];
}

// 256-thread LDS scan of block sums (nb <= 256)
__global__ void scan_top_par(int* __restrict__ bsums, int nb) {
  __shared__ int lds[2][256];
  int t = threadIdx.x;
  int v = (t < nb) ? bsums[t] : 0;
  lds[0][t] = v;
  __syncthreads();
  int cur = 0;
  for (int d2 = 1; d2 < 256; d2 <<= 1) {
    int val = lds[cur][t];
    if (t >= d2) val += lds[cur][t - d2];
    lds[cur ^ 1][t] = val;
    __syncthreads();
    cur ^= 1;
  }
  if (t < nb) bsums[t] = lds[cur][t] - v;  // exclusive
}

// rp is [2N+2]: rp1 = rp[0..N], rp2 = rp[N+1..2N+1]; values are COMBINED padded offsets.
__global__ void scan_final(const int* __restrict__ deg, const int* __restrict__ bsums,
                           int* __restrict__ rp, float* __restrict__ invdeg,
                           int n2, int Nn) {
  __shared__ int buf[2][256];
  int base = blockIdx.x * 1024;
  int v[4], p[4];
  int s = 0;
#pragma unroll
  for (int j = 0; j < 4; ++j) {
    int idx = base + threadIdx.x * 4 + j;
    v[j] = (idx < n2) ? deg[idx] : 0;
    p[j] = (v[j] + 3) & ~3;
    s += p[j];
  }
  buf[0][threadIdx.x] = s;
  __syncthreads();
  int cur = 0;
  for (int d2 = 1; d2 < 256; d2 <<= 1) {
    int val = buf[cur][threadIdx.x];
    if (threadIdx.x >= d2) val += buf[cur][threadIdx.x - d2];
    buf[cur ^ 1][threadIdx.x] = val;
    __syncthreads();
    cur ^= 1;
  }
  int run = buf[cur][threadIdx.x] - s + bsums[blockIdx.x];
#pragma unroll
  for (int j = 0; j < 4; ++j) {
    int idx = base + threadIdx.x * 4 + j;
    if (idx < n2) {
      int isB = idx >= Nn;
      rp[idx + isB] = run;          // combined padded offset
      int dv = v[j] < 1 ? 1 : v[j];
      invdeg[idx] = 1.0f / (float)dv;
      run += p[j];
      if (idx == Nn - 1) rp[Nn] = run;        // rp1 sentinel
      if (idx == n2 - 1) rp[n2 + 1] = run;    // rp2 sentinel
    }
  }
}

// pre-fill colC with dummy index N; zero the dummy rows of Hn1b/Hn2b
__global__ void fill_pad(int* __restrict__ colC, ushort* __restrict__ Hn1b,
                         ushort* __restrict__ Hn2b, int cap, int Nn) {
  int i = blockIdx.x * 256 + threadIdx.x;
  if (i < cap) colC[i] = Nn;
  if (blockIdx.x == 0 && threadIdx.x < D) {
    Hn1b[(size_t)Nn * D + threadIdx.x] = 0;
    Hn2b[(size_t)Nn * D + threadIdx.x] = 0;
  }
}

// ---- CSR fill pass: atomic-free (uses rank from count pass) ----
__global__ void fill_norank(const int* __restrict__ ei1, const int* __restrict__ ei2,
                            const int* __restrict__ rp, const int* __restrict__ rank,
                            int* __restrict__ colC, int E, int Nn) {
  int i = blockIdx.x * 256 + threadIdx.x;
  if (i < E) {
    int dst = ei1[E + i];
    colC[rp[dst] + rank[i]] = ei1[i];
  } else if (i < 2 * E) {
    int j = i - E;
    int dst = ei2[E + j];
    colC[rp[Nn + 1 + dst] + rank[i]] = ei2[j];
  }
}

// ------------- weight pack (both layers): B-fragment order, hi/lo split -------------
__global__ void wpack2(const float* __restrict__ W1n1, const float* __restrict__ W1n2,
                       const float* __restrict__ W1s1, const float* __restrict__ W1s2,
                       const float* __restrict__ W2n1, const float* __restrict__ W2n2,
                       const float* __restrict__ W2s1, const float* __restrict__ W2s2,
                       bf16x8* __restrict__ Wh1, bf16x8* __restrict__ Wl1,
                       bf16x8* __restrict__ Wh2, bf16x8* __restrict__ Wl2) {
  int bid = blockIdx.x;            // 0..47
  int layer = bid >= 24;
  int ct = bid - layer * 24;
  const float* Wn1 = layer ? W2n1 : W1n1;
  const float* Wn2 = layer ? W2n2 : W1n2;
  const float* Ws1 = layer ? W2s1 : W1s1;
  const float* Ws2 = layer ? W2s2 : W1s2;
  bf16x8* Wh = layer ? Wh2 : Wh1;
  bf16x8* Wl = layer ? Wl2 : Wl1;
  int ks = threadIdx.x >> 6;
  int l = threadIdx.x & 63;
  int col = (ct & 7) * 16 + (l & 15);
  int k0 = ks * 32 + (l >> 4) * 8;
  bf16x8 hv, lv;
#pragma unroll
  for (int j = 0; j < 8; ++j) {
    int k = k0 + j;
    float v;
    if (ct < 8)       v = Wn1[k * D + col];
    else if (ct < 16) v = Wn2[k * D + col];
    else              v = Ws1[k * D + col] + Ws2[k * D + col];
    ushort h = f2bf(v);
    float r = v - bf2f(h);
    hv[j] = (short)h;
    lv[j] = (short)f2bf(r);
  }
  int idx = (ct * 4 + ks) * 64 + l;
  Wh[idx] = hv;
  Wl[idx] = lv;
}

// ---------------- X pack into A-fragment order (hi/lo split) ----------------
__global__ void xpack(const float* __restrict__ X, bf16x8* __restrict__ Xh,
                      bf16x8* __restrict__ Xl, int M) {
  int g = blockIdx.x;
  int ks = threadIdx.x >> 6;
  int l = threadIdx.x & 63;
  int row = g * 16 + (l & 15);
  int c0 = ks * 32 + (l >> 4) * 8;
  bf16x8 hv, lv;
  if (row < M) {
    float4 a = *reinterpret_cast<const float4*>(X + (size_t)row * D + c0);
    float4 b = *reinterpret_cast<const float4*>(X + (size_t)row * D + c0 + 4);
    float xs[8] = {a.x, a.y, a.z, a.w, b.x, b.y, b.z, b.w};
#pragma unroll
    for (int j = 0; j < 8; ++j) {
      ushort h = f2bf(xs[j]);
      float r = xs[j] - bf2f(h);
      hv[j] = (short)h;
      lv[j] = (short)f2bf(r);
    }
  } else {
#pragma unroll
    for (int j = 0; j < 8; ++j) { hv[j] = 0; lv[j] = 0; }
  }
  int idx = (g * 4 + ks) * 64 + l;
  Xh[idx] = hv;
  Xl[idx] = lv;
}

// ------- MFMA GEMM: 32 rows/block, 8 waves, 3 col-tiles/wave (acc 24 AGPR) -------
__global__ __launch_bounds__(512) void gemm_mfma(
    const bf16x8* __restrict__ Xh, const bf16x8* __restrict__ Xl,
    const bf16x8* __restrict__ Wh, const bf16x8* __restrict__ Wl,
    ushort* __restrict__ Hn1b, ushort* __restrict__ Hn2b,
    ushort* __restrict__ Hsb, int M) {
  int w = __builtin_amdgcn_readfirstlane(threadIdx.x >> 6);  // 0..7
  int l = threadIdx.x & 63;
  int rb = blockIdx.x;   // 32-row tile

  f32x4 acc[2][3];
#pragma unroll
  for (int rt = 0; rt < 2; ++rt)
#pragma unroll
    for (int i = 0; i < 3; ++i)
      acc[rt][i] = (f32x4){0.f, 0.f, 0.f, 0.f};

#pragma unroll
  for (int ks = 0; ks < 4; ++ks) {
    bf16x8 Ah[2], Al[2];
#pragma unroll
    for (int rt = 0; rt < 2; ++rt) {
      int gi = ((rb * 2 + rt) * 4 + ks) * 64 + l;
      Ah[rt] = Xh[gi];
      Al[rt] = Xl[gi];
    }
#pragma unroll
    for (int i = 0; i < 3; ++i) {
      int ct = w + 8 * i;
      int wi = (ct * 4 + ks) * 64 + l;
      bf16x8 bh = Wh[wi];
      bf16x8 bl = Wl[wi];
#pragma unroll
      for (int rt = 0; rt < 2; ++rt) {
        acc[rt][i] = __builtin_amdgcn_mfma_f32_16x16x32_bf16(Ah[rt], bh, acc[rt][i], 0, 0, 0);
        acc[rt][i] = __builtin_amdgcn_mfma_f32_16x16x32_bf16(Ah[rt], bl, acc[rt][i], 0, 0, 0);
        acc[rt][i] = __builtin_amdgcn_mfma_f32_16x16x32_bf16(Al[rt], bh, acc[rt][i], 0, 0, 0);
      }
    }
  }

  int cq = l & 15;
  int rq = (l >> 4) * 4;
#pragma unroll
  for (int i = 0; i < 3; ++i) {
    int ct = w + 8 * i;  // wave-uniform
    ushort* dstbuf = (ct < 8) ? Hn1b : (ct < 16) ? Hn2b : Hsb;
    int cc = (ct & 7) * 16 + cq;
#pragma unroll
    for (int rt = 0; rt < 2; ++rt) {
      int R0 = rb * 32 + rt * 16 + rq;
#pragma unroll
      for (int r = 0; r < 4; ++r) {
        int R = R0 + r;
        if (R < M) dstbuf[(size_t)R * D + cc] = f2bf(acc[rt][i][r]);
      }
    }
  }
}

// ---- fused aggregation (padded CSR: no masks/clamps) + BN partial stats ----
__global__ __launch_bounds__(256) void fused_agg(
    ushort* __restrict__ Hsb, const ushort* __restrict__ Hn1b,
    const ushort* __restrict__ Hn2b,
    const int* __restrict__ rp1, const int* __restrict__ rp2,
    const int* __restrict__ colC,
    const float* __restrict__ inv1, const float* __restrict__ inv2,
    float* __restrict__ part_s, float* __restrict__ part_q, int Nn) {
  __shared__ float lds_s[4][128];
  __shared__ float lds_q[4][128];
  int wv = threadIdx.x >> 6;
  int l = threadIdx.x & 63;
  int n = blockIdx.x * 4 + wv;
  int t2 = l * 2;
  float c0 = 0.f, c1 = 0.f;
  if (n < Nn) {
    int b1 = rp1[n], e1 = rp1[n + 1];
    int b2 = rp2[n], e2 = rp2[n + 1];
    float i1 = inv1[n], i2 = inv2[n];
    int pd1 = e1 - b1, pd2 = e2 - b2;       // multiples of 4
    int lmax = pd1 > pd2 ? pd1 : pd2;
    float pa = 0.f, pb = 0.f, qa = 0.f, qb = 0.f;
    for (int a = 0; a < lmax; a += 4) {
      int4 cA = (a < pd1) ? *reinterpret_cast<const int4*>(colC + b1 + a)
                          : make_int4(Nn, Nn, Nn, Nn);
      int4 cB = (a < pd2) ? *reinterpret_cast<const int4*>(colC + b2 + a)
                          : make_int4(Nn, Nn, Nn, Nn);
      uint v10 = *reinterpret_cast<const uint*>(Hn1b + (size_t)cA.x * D + t2);
      uint v11 = *reinterpret_cast<const uint*>(Hn1b + (size_t)cA.y * D + t2);
      uint v12 = *reinterpret_cast<const uint*>(Hn1b + (size_t)cA.z * D + t2);
      uint v13 = *reinterpret_cast<const uint*>(Hn1b + (size_t)cA.w * D + t2);
      uint v20 = *reinterpret_cast<const uint*>(Hn2b + (size_t)cB.x * D + t2);
      uint v21 = *reinterpret_cast<const uint*>(Hn2b + (size_t)cB.y * D + t2);
      uint v22 = *reinterpret_cast<const uint*>(Hn2b + (size_t)cB.z * D + t2);
      uint v23 = *reinterpret_cast<const uint*>(Hn2b + (size_t)cB.w * D + t2);
      pa += (bf2f((ushort)(v10 & 0xFFFF)) + bf2f((ushort)(v11 & 0xFFFF))) +
            (bf2f((ushort)(v12 & 0xFFFF)) + bf2f((ushort)(v13 & 0xFFFF)));
      pb += (bf2f((ushort)(v10 >> 16)) + bf2f((ushort)(v11 >> 16))) +
            (bf2f((ushort)(v12 >> 16)) + bf2f((ushort)(v13 >> 16)));
      qa += (bf2f((ushort)(v20 & 0xFFFF)) + bf2f((ushort)(v21 & 0xFFFF))) +
            (bf2f((ushort)(v22 & 0xFFFF)) + bf2f((ushort)(v23 & 0xFFFF)));
      qb += (bf2f((ushort)(v20 >> 16)) + bf2f((ushort)(v21 >> 16))) +
            (bf2f((ushort)(v22 >> 16)) + bf2f((ushort)(v23 >> 16)));
    }
    uint sv = *reinterpret_cast<const uint*>(Hsb + (size_t)n * D + t2);
    c0 = bf2f((ushort)(sv & 0xFFFF)) + pa * i1 + qa * i2;
    c1 = bf2f((ushort)(sv >> 16)) + pb * i1 + qb * i2;
    ushort h0 = f2bf(c0), h1 = f2bf(c1);
    *reinterpret_cast<uint*>(Hsb + (size_t)n * D + t2) = ((uint)h1 << 16) | (uint)h0;
    c0 = bf2f(h0);  // stats on stored (rounded) values: self-consistent BN
    c1 = bf2f(h1);
  }
  lds_s[wv][t2] = c0;
  lds_s[wv][t2 + 1] = c1;
  lds_q[wv][t2] = c0 * c0;
  lds_q[wv][t2 + 1] = c1 * c1;
  __syncthreads();
  if (threadIdx.x < 128) {
    int c = threadIdx.x;
    float s = lds_s[0][c] + lds_s[1][c] + lds_s[2][c] + lds_s[3][c];
    float q = lds_q[0][c] + lds_q[1][c] + lds_q[2][c] + lds_q[3][c];
    int slot = (blockIdx.x & 63) * 128 + c;
    atomicAdd(&part_s[slot], s);
    atomicAdd(&part_q[slot], q);
  }
}

// ---- finalize BN: partials -> per-column affine coef; re-zero partials ----
__global__ void bn_finalize(float* __restrict__ part_s, float* __restrict__ part_q,
                            const float* __restrict__ g, const float* __restrict__ b,
                            float* __restrict__ coef, float invM) {
  int c = threadIdx.x;
  if (c >= D) return;
  float s = 0.f, q = 0.f;
#pragma unroll 4
  for (int i = 0; i < 64; ++i) {
    s += part_s[i * 128 + c];
    part_s[i * 128 + c] = 0.f;
    q += part_q[i * 128 + c];
    part_q[i * 128 + c] = 0.f;
  }
  float mean = s * invM;
  float var = q * invM - mean * mean;
  float sc = rsqrtf(var + EPS) * g[c];
  coef[c] = sc;
  coef[D + c] = b[c] - mean * sc;
}

// ---- BN(affine)+LeakyReLU applied to Hsb; split-pack into A-fragment order ----
__global__ void bn_apply_pack(const ushort* __restrict__ Hsb, const float* __restrict__ coef,
                              bf16x8* __restrict__ Ah, bf16x8* __restrict__ Al, int M) {
  int g = blockIdx.x;
  int ks = threadIdx.x >> 6;
  int l = threadIdx.x & 63;
  int row = g * 16 + (l & 15);
  int c0 = ks * 32 + (l >> 4) * 8;
  bf16x8 hv, lv;
  if (row < M) {
    bf16x8 in = *reinterpret_cast<const bf16x8*>(Hsb + (size_t)row * D + c0);
#pragma unroll
    for (int j = 0; j < 8; ++j) {
      int c = c0 + j;
      float v = fmaf(bf2f((ushort)in[j]), coef[c], coef[D + c]);
      v = v > 0.f ? v : SLOPE * v;
      ushort h = f2bf(v);
      float r = v - bf2f(h);
      hv[j] = (short)h;
      lv[j] = (short)f2bf(r);
    }
  } else {
#pragma unroll
    for (int j = 0; j < 8; ++j) { hv[j] = 0; lv[j] = 0; }
  }
  int idx = (g * 4 + ks) * 64 + l;
  Ah[idx] = hv;
  Al[idx] = lv;
}

// ------- edge-label dots: gather bf16 rows, BN affine applied inline -------
__global__ void edge_dot_bn(const ushort* __restrict__ Hb, const float* __restrict__ coef,
                            const int* __restrict__ ea, const int* __restrict__ eb,
                            float* __restrict__ out, int EL) {
  int tt = blockIdx.x * 256 + threadIdx.x;
  int e = tt >> 4, l = tt & 15;
  if (e >= EL) return;
  int cb = l * 8;
  float4 sc0 = *reinterpret_cast<const float4*>(coef + cb);
  float4 sc1 = *reinterpret_cast<const float4*>(coef + cb + 4);
  float4 sh0 = *reinterpret_cast<const float4*>(coef + D + cb);
  float4 sh1 = *reinterpret_cast<const float4*>(coef + D + cb + 4);
  float sc[8] = {sc0.x, sc0.y, sc0.z, sc0.w, sc1.x, sc1.y, sc1.z, sc1.w};
  float sh[8] = {sh0.x, sh0.y, sh0.z, sh0.w, sh1.x, sh1.y, sh1.z, sh1.w};
  bf16x8 av = *reinterpret_cast<const bf16x8*>(Hb + (size_t)ea[e] * D + cb);
  bf16x8 bv = *reinterpret_cast<const bf16x8*>(Hb + (size_t)eb[e] * D + cb);
  float d = 0.f;
#pragma unroll
  for (int j = 0; j < 8; ++j) {
    float fa = fmaf(bf2f((ushort)av[j]), sc[j], sh[j]);
    float fb = fmaf(bf2f((ushort)bv[j]), sc[j], sh[j]);
    d = fmaf(fa, fb, d);
  }
  d += __shfl_xor(d, 1);
  d += __shfl_xor(d, 2);
  d += __shfl_xor(d, 4);
  d += __shfl_xor(d, 8);
  if (l == 0) out[e] = d;
}

// ---------------- launch ----------------
extern "C" void kernel_launch(void* const* d_in, const int* in_sizes, int n_in,
                              void* d_out, int out_size, void* d_ws, size_t ws_size,
                              hipStream_t stream) {
  const float* x    = (const float*)d_in[0];
  const int* ei1    = (const int*)d_in[1];
  const int* ei2    = (const int*)d_in[2];
  const int* eli    = (const int*)d_in[3];
  const float* W1n1 = (const float*)d_in[4];
  const float* W1s1 = (const float*)d_in[5];
  const float* W1n2 = (const float*)d_in[6];
  const float* W1s2 = (const float*)d_in[7];
  const float* W2n1 = (const float*)d_in[8];
  const float* W2s1 = (const float*)d_in[9];
  const float* W2n2 = (const float*)d_in[10];
  const float* W2s2 = (const float*)d_in[11];
  const float* g1   = (const float*)d_in[12];
  const float* b1   = (const float*)d_in[13];
  const float* g2   = (const float*)d_in[14];
  const float* b2   = (const float*)d_in[15];
  float* out = (float*)d_out;

  const int N = NN, E = NE;
  const int EL = in_sizes[3] / 2;
  const int RB = (N + 31) / 32;       // 32-row gemm blocks (3125)
  const int G = RB * 2;               // 16-row A-fragment tiles (6250)
  const int N2 = 2 * N;

  char* w = (char*)d_ws;
  // zeroed region (one memset): deg[2N], part_s, part_q
  int* deg = (int*)w; w += (size_t)N2 * 4;
  float* part_s = (float*)w; w += (size_t)64 * 128 * 4;
  float* part_q = (float*)w; w += (size_t)64 * 128 * 4;
  size_t zbytes = (size_t)(N2 + 2 * 64 * 128) * 4;

  bf16x8* Xh = (bf16x8*)w; w += (size_t)G * 4 * 64 * 16;
  bf16x8* Xl = (bf16x8*)w; w += (size_t)G * 4 * 64 * 16;
  ushort* Hn1b = (ushort*)w; w += (size_t)(N + 1) * D * 2;   // +1 dummy zero row
  ushort* Hn2b = (ushort*)w; w += (size_t)(N + 1) * D * 2;   // +1 dummy zero row
  ushort* Hsb  = (ushort*)w; w += (size_t)N * D * 2;
  bf16x8* Wh1 = (bf16x8*)w; w += (size_t)24 * 4 * 64 * 16;
  bf16x8* Wl1 = (bf16x8*)w; w += (size_t)24 * 4 * 64 * 16;
  bf16x8* Wh2 = (bf16x8*)w; w += (size_t)24 * 4 * 64 * 16;
  bf16x8* Wl2 = (bf16x8*)w; w += (size_t)24 * 4 * 64 * 16;
  int* rp   = (int*)w; w += (size_t)(N2 + 2) * 4;   // rp1 = rp[0..N], rp2 = rp[N+1..2N+1]
  int* rank = (int*)w; w += (size_t)2 * E * 4;      // per-edge rank within dst segment
  int* colC = (int*)w; w += (size_t)COLCAP * 4;     // combined padded col array
  float* inv = (float*)w; w += (size_t)N2 * 4;      // inv1 = inv, inv2 = inv + N
  int* bsums = (int*)w; w += 256 * 4;
  float* coef1 = (float*)w; w += 2 * D * 4;
  float* coef2 = (float*)w; w += 2 * D * 4;

  hipMemsetAsync(deg, 0, zbytes, stream);

  int e2b = (2 * E + 255) / 256;
  count_rank<<<e2b, 256, 0, stream>>>(ei1, ei2, E, deg, rank, N);
  int nb = (N2 + 1023) / 1024;  // 196
  scan_block_sums<<<nb, 256, 0, stream>>>(deg, bsums, N2);
  scan_top_par<<<1, 256, 0, stream>>>(bsums, nb);
  scan_final<<<nb, 256, 0, stream>>>(deg, bsums, rp, inv, N2, N);
  fill_pad<<<(COLCAP + 255) / 256, 256, 0, stream>>>(colC, Hn1b, Hn2b, COLCAP, N);
  fill_norank<<<e2b, 256, 0, stream>>>(ei1, ei2, rp, rank, colC, E, N);

  wpack2<<<48, 256, 0, stream>>>(W1n1, W1n2, W1s1, W1s2, W2n1, W2n2, W2s1, W2s2,
                                 Wh1, Wl1, Wh2, Wl2);
  xpack<<<G, 256, 0, stream>>>(x, Xh, Xl, N);

  int agb = (N + 3) / 4;
  int* rp2p = rp + N + 1;

  // ---- Layer 1 ----
  gemm_mfma<<<RB, 512, 0, stream>>>(Xh, Xl, Wh1, Wl1, Hn1b, Hn2b, Hsb, N);
  fused_agg<<<agb, 256, 0, stream>>>(Hsb, Hn1b, Hn2b, rp, rp2p, colC, inv, inv + N,
                                     part_s, part_q, N);
  bn_finalize<<<1, 128, 0, stream>>>(part_s, part_q, g1, b1, coef1, 1.0f / N);
  bn_apply_pack<<<G, 256, 0, stream>>>(Hsb, coef1, Xh, Xl, N);  // overwrite X packs

  // ---- Layer 2 ----
  gemm_mfma<<<RB, 512, 0, stream>>>(Xh, Xl, Wh2, Wl2, Hn1b, Hn2b, Hsb, N);
  fused_agg<<<agb, 256, 0, stream>>>(Hsb, Hn1b, Hn2b, rp, rp2p, colC, inv, inv + N,
                                     part_s, part_q, N);
  bn_finalize<<<1, 128, 0, stream>>>(part_s, part_q, g2, b2, coef2, 1.0f / N);

  // ---- edge-label dots (bf16 gathers, BN affine fused) ----
  int db = (int)(((size_t)EL * 16 + 255) / 256);
  edge_dot_bn<<<db, 256, 0, stream>>>(Hsb, coef2, eli, eli + EL, out, EL);
}

// Round 11
// 365.566 us; speedup vs baseline: 2.9997x; 1.0168x over previous
//
#include <hip/hip_runtime.h>

#define NN 100000
#define NE 500000
#define D 128
#define EPS 1e-5f
#define SLOPE 0.01f
#define COLCAP (2 * NE + 6 * NN + 64)   // worst-case combined padded col entries

typedef short bf16x8 __attribute__((ext_vector_type(8)));
typedef float f32x4 __attribute__((ext_vector_type(4)));

__device__ __forceinline__ ushort f2bf(float x) {
  uint u = __float_as_uint(x);
  u += 0x7FFF + ((u >> 16) & 1);
  return (ushort)(u >> 16);
}
__device__ __forceinline__ float bf2f(ushort h) {
  return __uint_as_float(((uint)h) << 16);
}

// ---- CSR count pass: histogram via atomics, storing each edge's rank (atomic return) ----
// deg is combined [2N]: deg1 = deg, deg2 = deg + N. rank is combined [2E].
__global__ void count_rank(const int* __restrict__ ei1, const int* __restrict__ ei2,
                           int E, int* __restrict__ deg, int* __restrict__ rank, int Nn) {
  int i = blockIdx.x * 256 + threadIdx.x;
  if (i < E) {
    rank[i] = atomicAdd(&deg[ei1[E + i]], 1);
  } else if (i < 2 * E) {
    int j = i - E;
    rank[i] = atomicAdd(&deg[Nn + ei2[E + j]], 1);
  }
}

// ---- combined multi-block exclusive scan over PADDED deg[2N] (pad to multiple of 4) ----
__global__ void scan_block_sums(const int* __restrict__ deg, int* __restrict__ bsums, int n2) {
  __shared__ int red[256];
  int base = blockIdx.x * 1024;
  int s = 0;
  for (int i = threadIdx.x; i < 1024; i += 256) {
    int idx = base + i;
    if (idx < n2) s += (deg[idx] + 3) & ~3;
  }
  red[threadIdx.x] = s;
  __syncthreads();
  for (int off = 128; off > 0; off >>= 1) {
    if (threadIdx.x < off) red[threadIdx.x] += red[threadIdx.x + off];
    __syncthreads();
  }
  if (threadIdx.x == 0) bsums[blockIdx.x] = red[0];
}

// 256-thread LDS scan of block sums (nb <= 256)
__global__ void scan_top_par(int* __restrict__ bsums, int nb) {
  __shared__ int lds[2][256];
  int t = threadIdx.x;
  int v = (t < nb) ? bsums[t] : 0;
  lds[0][t] = v;
  __syncthreads();
  int cur = 0;
  for (int d2 = 1; d2 < 256; d2 <<= 1) {
    int val = lds[cur][t];
    if (t >= d2) val += lds[cur][t - d2];
    lds[cur ^ 1][t] = val;
    __syncthreads();
    cur ^= 1;
  }
  if (t < nb) bsums[t] = lds[cur][t] - v;  // exclusive
}

// rp is [2N+2]: rp1 = rp[0..N], rp2 = rp[N+1..2N+1]; values are COMBINED padded offsets.
// Also writes the per-node PAD entries of colC (dummy index N) and zeroes dummy rows.
__global__ void scan_final(const int* __restrict__ deg, const int* __restrict__ bsums,
                           int* __restrict__ rp, float* __restrict__ invdeg,
                           int* __restrict__ colC,
                           ushort* __restrict__ Hn1b, ushort* __restrict__ Hn2b,
                           int n2, int Nn) {
  __shared__ int buf[2][256];
  int base = blockIdx.x * 1024;
  int v[4], p[4];
  int s = 0;
#pragma unroll
  for (int j = 0; j < 4; ++j) {
    int idx = base + threadIdx.x * 4 + j;
    v[j] = (idx < n2) ? deg[idx] : 0;
    p[j] = (v[j] + 3) & ~3;
    s += p[j];
  }
  buf[0][threadIdx.x] = s;
  __syncthreads();
  int cur = 0;
  for (int d2 = 1; d2 < 256; d2 <<= 1) {
    int val = buf[cur][threadIdx.x];
    if (threadIdx.x >= d2) val += buf[cur][threadIdx.x - d2];
    buf[cur ^ 1][threadIdx.x] = val;
    __syncthreads();
    cur ^= 1;
  }
  int run = buf[cur][threadIdx.x] - s + bsums[blockIdx.x];
#pragma unroll
  for (int j = 0; j < 4; ++j) {
    int idx = base + threadIdx.x * 4 + j;
    if (idx < n2) {
      int isB = idx >= Nn;
      rp[idx + isB] = run;          // combined padded offset
      int dv = v[j] < 1 ? 1 : v[j];
      invdeg[idx] = 1.0f / (float)dv;
      for (int q = v[j]; q < p[j]; ++q) colC[run + q] = Nn;  // pad slots only
      run += p[j];
      if (idx == Nn - 1) rp[Nn] = run;        // rp1 sentinel
      if (idx == n2 - 1) rp[n2 + 1] = run;    // rp2 sentinel
    }
  }
  if (blockIdx.x == 0 && threadIdx.x < D) {   // zero the dummy gather rows
    Hn1b[(size_t)Nn * D + threadIdx.x] = 0;
    Hn2b[(size_t)Nn * D + threadIdx.x] = 0;
  }
}

// ---- CSR fill pass: atomic-free (uses rank from count pass) ----
__global__ void fill_norank(const int* __restrict__ ei1, const int* __restrict__ ei2,
                            const int* __restrict__ rp, const int* __restrict__ rank,
                            int* __restrict__ colC, int E, int Nn) {
  int i = blockIdx.x * 256 + threadIdx.x;
  if (i < E) {
    int dst = ei1[E + i];
    colC[rp[dst] + rank[i]] = ei1[i];
  } else if (i < 2 * E) {
    int j = i - E;
    int dst = ei2[E + j];
    colC[rp[Nn + 1 + dst] + rank[i]] = ei2[j];
  }
}

// ---- merged pack: blocks 0..47 pack weights (both layers); blocks 48+ pack X ----
__global__ void pack_all(const float* __restrict__ W1n1, const float* __restrict__ W1n2,
                         const float* __restrict__ W1s1, const float* __restrict__ W1s2,
                         const float* __restrict__ W2n1, const float* __restrict__ W2n2,
                         const float* __restrict__ W2s1, const float* __restrict__ W2s2,
                         bf16x8* __restrict__ Wh1, bf16x8* __restrict__ Wl1,
                         bf16x8* __restrict__ Wh2, bf16x8* __restrict__ Wl2,
                         const float* __restrict__ X, bf16x8* __restrict__ Xh,
                         bf16x8* __restrict__ Xl, int M) {
  int bid = blockIdx.x;
  int ks = threadIdx.x >> 6;
  int l = threadIdx.x & 63;
  if (bid < 48) {
    int layer = bid >= 24;
    int ct = bid - layer * 24;
    const float* Wn1 = layer ? W2n1 : W1n1;
    const float* Wn2 = layer ? W2n2 : W1n2;
    const float* Ws1 = layer ? W2s1 : W1s1;
    const float* Ws2 = layer ? W2s2 : W1s2;
    bf16x8* Wh = layer ? Wh2 : Wh1;
    bf16x8* Wl = layer ? Wl2 : Wl1;
    int col = (ct & 7) * 16 + (l & 15);
    int k0 = ks * 32 + (l >> 4) * 8;
    bf16x8 hv, lv;
#pragma unroll
    for (int j = 0; j < 8; ++j) {
      int k = k0 + j;
      float v;
      if (ct < 8)       v = Wn1[k * D + col];
      else if (ct < 16) v = Wn2[k * D + col];
      else              v = Ws1[k * D + col] + Ws2[k * D + col];
      ushort h = f2bf(v);
      float r = v - bf2f(h);
      hv[j] = (short)h;
      lv[j] = (short)f2bf(r);
    }
    int idx = (ct * 4 + ks) * 64 + l;
    Wh[idx] = hv;
    Wl[idx] = lv;
  } else {
    int g = bid - 48;
    int row = g * 16 + (l & 15);
    int c0 = ks * 32 + (l >> 4) * 8;
    bf16x8 hv, lv;
    if (row < M) {
      float4 a = *reinterpret_cast<const float4*>(X + (size_t)row * D + c0);
      float4 b = *reinterpret_cast<const float4*>(X + (size_t)row * D + c0 + 4);
      float xs[8] = {a.x, a.y, a.z, a.w, b.x, b.y, b.z, b.w};
#pragma unroll
      for (int j = 0; j < 8; ++j) {
        ushort h = f2bf(xs[j]);
        float r = xs[j] - bf2f(h);
        hv[j] = (short)h;
        lv[j] = (short)f2bf(r);
      }
    } else {
#pragma unroll
      for (int j = 0; j < 8; ++j) { hv[j] = 0; lv[j] = 0; }
    }
    int idx = (g * 4 + ks) * 64 + l;
    Xh[idx] = hv;
    Xl[idx] = lv;
  }
}

// ------- MFMA GEMM: 32 rows/block, 8 waves, 3 col-tiles/wave (acc 24 AGPR) -------
__global__ __launch_bounds__(512) void gemm_mfma(
    const bf16x8* __restrict__ Xh, const bf16x8* __restrict__ Xl,
    const bf16x8* __restrict__ Wh, const bf16x8* __restrict__ Wl,
    ushort* __restrict__ Hn1b, ushort* __restrict__ Hn2b,
    ushort* __restrict__ Hsb, int M) {
  int w = __builtin_amdgcn_readfirstlane(threadIdx.x >> 6);  // 0..7
  int l = threadIdx.x & 63;
  int rb = blockIdx.x;   // 32-row tile

  f32x4 acc[2][3];
#pragma unroll
  for (int rt = 0; rt < 2; ++rt)
#pragma unroll
    for (int i = 0; i < 3; ++i)
      acc[rt][i] = (f32x4){0.f, 0.f, 0.f, 0.f};

#pragma unroll
  for (int ks = 0; ks < 4; ++ks) {
    bf16x8 Ah[2], Al[2];
#pragma unroll
    for (int rt = 0; rt < 2; ++rt) {
      int gi = ((rb * 2 + rt) * 4 + ks) * 64 + l;
      Ah[rt] = Xh[gi];
      Al[rt] = Xl[gi];
    }
#pragma unroll
    for (int i = 0; i < 3; ++i) {
      int ct = w + 8 * i;
      int wi = (ct * 4 + ks) * 64 + l;
      bf16x8 bh = Wh[wi];
      bf16x8 bl = Wl[wi];
#pragma unroll
      for (int rt = 0; rt < 2; ++rt) {
        acc[rt][i] = __builtin_amdgcn_mfma_f32_16x16x32_bf16(Ah[rt], bh, acc[rt][i], 0, 0, 0);
        acc[rt][i] = __builtin_amdgcn_mfma_f32_16x16x32_bf16(Ah[rt], bl, acc[rt][i], 0, 0, 0);
        acc[rt][i] = __builtin_amdgcn_mfma_f32_16x16x32_bf16(Al[rt], bh, acc[rt][i], 0, 0, 0);
      }
    }
  }

  int cq = l & 15;
  int rq = (l >> 4) * 4;
#pragma unroll
  for (int i = 0; i < 3; ++i) {
    int ct = w + 8 * i;  // wave-uniform
    ushort* dstbuf = (ct < 8) ? Hn1b : (ct < 16) ? Hn2b : Hsb;
    int cc = (ct & 7) * 16 + cq;
#pragma unroll
    for (int rt = 0; rt < 2; ++rt) {
      int R0 = rb * 32 + rt * 16 + rq;
#pragma unroll
      for (int r = 0; r < 4; ++r) {
        int R = R0 + r;
        if (R < M) dstbuf[(size_t)R * D + cc] = f2bf(acc[rt][i][r]);
      }
    }
  }
}

// ---- fused aggregation (padded CSR: no masks/clamps) + BN partial stats ----
__global__ __launch_bounds__(256) void fused_agg(
    ushort* __restrict__ Hsb, const ushort* __restrict__ Hn1b,
    const ushort* __restrict__ Hn2b,
    const int* __restrict__ rp1, const int* __restrict__ rp2,
    const int* __restrict__ colC,
    const float* __restrict__ inv1, const float* __restrict__ inv2,
    float* __restrict__ part_s, float* __restrict__ part_q, int Nn) {
  __shared__ float lds_s[4][128];
  __shared__ float lds_q[4][128];
  int wv = threadIdx.x >> 6;
  int l = threadIdx.x & 63;
  int n = blockIdx.x * 4 + wv;
  int t2 = l * 2;
  float c0 = 0.f, c1 = 0.f;
  if (n < Nn) {
    int b1 = rp1[n], e1 = rp1[n + 1];
    int b2 = rp2[n], e2 = rp2[n + 1];
    float i1 = inv1[n], i2 = inv2[n];
    int pd1 = e1 - b1, pd2 = e2 - b2;       // multiples of 4
    int lmax = pd1 > pd2 ? pd1 : pd2;
    float pa = 0.f, pb = 0.f, qa = 0.f, qb = 0.f;
    for (int a = 0; a < lmax; a += 4) {
      int4 cA = (a < pd1) ? *reinterpret_cast<const int4*>(colC + b1 + a)
                          : make_int4(Nn, Nn, Nn, Nn);
      int4 cB = (a < pd2) ? *reinterpret_cast<const int4*>(colC + b2 + a)
                          : make_int4(Nn, Nn, Nn, Nn);
      uint v10 = *reinterpret_cast<const uint*>(Hn1b + (size_t)cA.x * D + t2);
      uint v11 = *reinterpret_cast<const uint*>(Hn1b + (size_t)cA.y * D + t2);
      uint v12 = *reinterpret_cast<const uint*>(Hn1b + (size_t)cA.z * D + t2);
      uint v13 = *reinterpret_cast<const uint*>(Hn1b + (size_t)cA.w * D + t2);
      uint v20 = *reinterpret_cast<const uint*>(Hn2b + (size_t)cB.x * D + t2);
      uint v21 = *reinterpret_cast<const uint*>(Hn2b + (size_t)cB.y * D + t2);
      uint v22 = *reinterpret_cast<const uint*>(Hn2b + (size_t)cB.z * D + t2);
      uint v23 = *reinterpret_cast<const uint*>(Hn2b + (size_t)cB.w * D + t2);
      pa += (bf2f((ushort)(v10 & 0xFFFF)) + bf2f((ushort)(v11 & 0xFFFF))) +
            (bf2f((ushort)(v12 & 0xFFFF)) + bf2f((ushort)(v13 & 0xFFFF)));
      pb += (bf2f((ushort)(v10 >> 16)) + bf2f((ushort)(v11 >> 16))) +
            (bf2f((ushort)(v12 >> 16)) + bf2f((ushort)(v13 >> 16)));
      qa += (bf2f((ushort)(v20 & 0xFFFF)) + bf2f((ushort)(v21 & 0xFFFF))) +
            (bf2f((ushort)(v22 & 0xFFFF)) + bf2f((ushort)(v23 & 0xFFFF)));
      qb += (bf2f((ushort)(v20 >> 16)) + bf2f((ushort)(v21 >> 16))) +
            (bf2f((ushort)(v22 >> 16)) + bf2f((ushort)(v23 >> 16)));
    }
    uint sv = *reinterpret_cast<const uint*>(Hsb + (size_t)n * D + t2);
    c0 = bf2f((ushort)(sv & 0xFFFF)) + pa * i1 + qa * i2;
    c1 = bf2f((ushort)(sv >> 16)) + pb * i1 + qb * i2;
    ushort h0 = f2bf(c0), h1 = f2bf(c1);
    *reinterpret_cast<uint*>(Hsb + (size_t)n * D + t2) = ((uint)h1 << 16) | (uint)h0;
    c0 = bf2f(h0);  // stats on stored (rounded) values: self-consistent BN
    c1 = bf2f(h1);
  }
  lds_s[wv][t2] = c0;
  lds_s[wv][t2 + 1] = c1;
  lds_q[wv][t2] = c0 * c0;
  lds_q[wv][t2 + 1] = c1 * c1;
  __syncthreads();
  if (threadIdx.x < 128) {
    int c = threadIdx.x;
    float s = lds_s[0][c] + lds_s[1][c] + lds_s[2][c] + lds_s[3][c];
    float q = lds_q[0][c] + lds_q[1][c] + lds_q[2][c] + lds_q[3][c];
    int slot = (blockIdx.x & 63) * 128 + c;
    atomicAdd(&part_s[slot], s);
    atomicAdd(&part_q[slot], q);
  }
}

// ---- finalize BN: partials -> per-column affine coef; re-zero partials ----
__global__ void bn_finalize(float* __restrict__ part_s, float* __restrict__ part_q,
                            const float* __restrict__ g, const float* __restrict__ b,
                            float* __restrict__ coef, float invM) {
  int c = threadIdx.x;
  if (c >= D) return;
  float s = 0.f, q = 0.f;
#pragma unroll 4
  for (int i = 0; i < 64; ++i) {
    s += part_s[i * 128 + c];
    part_s[i * 128 + c] = 0.f;
    q += part_q[i * 128 + c];
    part_q[i * 128 + c] = 0.f;
  }
  float mean = s * invM;
  float var = q * invM - mean * mean;
  float sc = rsqrtf(var + EPS) * g[c];
  coef[c] = sc;
  coef[D + c] = b[c] - mean * sc;
}

// ---- BN(affine)+LeakyReLU applied to Hsb; split-pack into A-fragment order ----
__global__ void bn_apply_pack(const ushort* __restrict__ Hsb, const float* __restrict__ coef,
                              bf16x8* __restrict__ Ah, bf16x8* __restrict__ Al, int M) {
  int g = blockIdx.x;
  int ks = threadIdx.x >> 6;
  int l = threadIdx.x & 63;
  int row = g * 16 + (l & 15);
  int c0 = ks * 32 + (l >> 4) * 8;
  bf16x8 hv, lv;
  if (row < M) {
    bf16x8 in = *reinterpret_cast<const bf16x8*>(Hsb + (size_t)row * D + c0);
#pragma unroll
    for (int j = 0; j < 8; ++j) {
      int c = c0 + j;
      float v = fmaf(bf2f((ushort)in[j]), coef[c], coef[D + c]);
      v = v > 0.f ? v : SLOPE * v;
      ushort h = f2bf(v);
      float r = v - bf2f(h);
      hv[j] = (short)h;
      lv[j] = (short)f2bf(r);
    }
  } else {
#pragma unroll
    for (int j = 0; j < 8; ++j) { hv[j] = 0; lv[j] = 0; }
  }
  int idx = (g * 4 + ks) * 64 + l;
  Ah[idx] = hv;
  Al[idx] = lv;
}

// ------- edge-label dots: gather bf16 rows, BN affine applied inline -------
__global__ void edge_dot_bn(const ushort* __restrict__ Hb, const float* __restrict__ coef,
                            const int* __restrict__ ea, const int* __restrict__ eb,
                            float* __restrict__ out, int EL) {
  int tt = blockIdx.x * 256 + threadIdx.x;
  int e = tt >> 4, l = tt & 15;
  if (e >= EL) return;
  int cb = l * 8;
  float4 sc0 = *reinterpret_cast<const float4*>(coef + cb);
  float4 sc1 = *reinterpret_cast<const float4*>(coef + cb + 4);
  float4 sh0 = *reinterpret_cast<const float4*>(coef + D + cb);
  float4 sh1 = *reinterpret_cast<const float4*>(coef + D + cb + 4);
  float sc[8] = {sc0.x, sc0.y, sc0.z, sc0.w, sc1.x, sc1.y, sc1.z, sc1.w};
  float sh[8] = {sh0.x, sh0.y, sh0.z, sh0.w, sh1.x, sh1.y, sh1.z, sh1.w};
  bf16x8 av = *reinterpret_cast<const bf16x8*>(Hb + (size_t)ea[e] * D + cb);
  bf16x8 bv = *reinterpret_cast<const bf16x8*>(Hb + (size_t)eb[e] * D + cb);
  float d = 0.f;
#pragma unroll
  for (int j = 0; j < 8; ++j) {
    float fa = fmaf(bf2f((ushort)av[j]), sc[j], sh[j]);
    float fb = fmaf(bf2f((ushort)bv[j]), sc[j], sh[j]);
    d = fmaf(fa, fb, d);
  }
  d += __shfl_xor(d, 1);
  d += __shfl_xor(d, 2);
  d += __shfl_xor(d, 4);
  d += __shfl_xor(d, 8);
  if (l == 0) out[e] = d;
}

// ---------------- launch ----------------
extern "C" void kernel_launch(void* const* d_in, const int* in_sizes, int n_in,
                              void* d_out, int out_size, void* d_ws, size_t ws_size,
                              hipStream_t stream) {
  const float* x    = (const float*)d_in[0];
  const int* ei1    = (const int*)d_in[1];
  const int* ei2    = (const int*)d_in[2];
  const int* eli    = (const int*)d_in[3];
  const float* W1n1 = (const float*)d_in[4];
  const float* W1s1 = (const float*)d_in[5];
  const float* W1n2 = (const float*)d_in[6];
  const float* W1s2 = (const float*)d_in[7];
  const float* W2n1 = (const float*)d_in[8];
  const float* W2s1 = (const float*)d_in[9];
  const float* W2n2 = (const float*)d_in[10];
  const float* W2s2 = (const float*)d_in[11];
  const float* g1   = (const float*)d_in[12];
  const float* b1   = (const float*)d_in[13];
  const float* g2   = (const float*)d_in[14];
  const float* b2   = (const float*)d_in[15];
  float* out = (float*)d_out;

  const int N = NN, E = NE;
  const int EL = in_sizes[3] / 2;
  const int RB = (N + 31) / 32;       // 32-row gemm blocks (3125)
  const int G = RB * 2;               // 16-row A-fragment tiles (6250)
  const int N2 = 2 * N;

  char* w = (char*)d_ws;
  // zeroed region (one memset): deg[2N], part_s, part_q
  int* deg = (int*)w; w += (size_t)N2 * 4;
  float* part_s = (float*)w; w += (size_t)64 * 128 * 4;
  float* part_q = (float*)w; w += (size_t)64 * 128 * 4;
  size_t zbytes = (size_t)(N2 + 2 * 64 * 128) * 4;

  bf16x8* Xh = (bf16x8*)w; w += (size_t)G * 4 * 64 * 16;
  bf16x8* Xl = (bf16x8*)w; w += (size_t)G * 4 * 64 * 16;
  ushort* Hn1b = (ushort*)w; w += (size_t)(N + 1) * D * 2;   // +1 dummy zero row
  ushort* Hn2b = (ushort*)w; w += (size_t)(N + 1) * D * 2;   // +1 dummy zero row
  ushort* Hsb  = (ushort*)w; w += (size_t)N * D * 2;
  bf16x8* Wh1 = (bf16x8*)w; w += (size_t)24 * 4 * 64 * 16;
  bf16x8* Wl1 = (bf16x8*)w; w += (size_t)24 * 4 * 64 * 16;
  bf16x8* Wh2 = (bf16x8*)w; w += (size_t)24 * 4 * 64 * 16;
  bf16x8* Wl2 = (bf16x8*)w; w += (size_t)24 * 4 * 64 * 16;
  int* rp   = (int*)w; w += (size_t)(N2 + 2) * 4;   // rp1 = rp[0..N], rp2 = rp[N+1..2N+1]
  int* rank = (int*)w; w += (size_t)2 * E * 4;      // per-edge rank within dst segment
  int* colC = (int*)w; w += (size_t)COLCAP * 4;     // combined padded col array
  float* inv = (float*)w; w += (size_t)N2 * 4;      // inv1 = inv, inv2 = inv + N
  int* bsums = (int*)w; w += 256 * 4;
  float* coef1 = (float*)w; w += 2 * D * 4;
  float* coef2 = (float*)w; w += 2 * D * 4;

  hipMemsetAsync(deg, 0, zbytes, stream);

  int e2b = (2 * E + 255) / 256;
  count_rank<<<e2b, 256, 0, stream>>>(ei1, ei2, E, deg, rank, N);
  int nb = (N2 + 1023) / 1024;  // 196
  scan_block_sums<<<nb, 256, 0, stream>>>(deg, bsums, N2);
  scan_top_par<<<1, 256, 0, stream>>>(bsums, nb);
  scan_final<<<nb, 256, 0, stream>>>(deg, bsums, rp, inv, colC, Hn1b, Hn2b, N2, N);
  fill_norank<<<e2b, 256, 0, stream>>>(ei1, ei2, rp, rank, colC, E, N);

  pack_all<<<48 + G, 256, 0, stream>>>(W1n1, W1n2, W1s1, W1s2, W2n1, W2n2, W2s1, W2s2,
                                       Wh1, Wl1, Wh2, Wl2, x, Xh, Xl, N);

  int agb = (N + 3) / 4;
  int* rp2p = rp + N + 1;

  // ---- Layer 1 ----
  gemm_mfma<<<RB, 512, 0, stream>>>(Xh, Xl, Wh1, Wl1, Hn1b, Hn2b, Hsb, N);
  fused_agg<<<agb, 256, 0, stream>>>(Hsb, Hn1b, Hn2b, rp, rp2p, colC, inv, inv + N,
                                     part_s, part_q, N);
  bn_finalize<<<1, 128, 0, stream>>>(part_s, part_q, g1, b1, coef1, 1.0f / N);
  bn_apply_pack<<<G, 256, 0, stream>>>(Hsb, coef1, Xh, Xl, N);  // overwrite X packs

  // ---- Layer 2 ----
  gemm_mfma<<<RB, 512, 0, stream>>>(Xh, Xl, Wh2, Wl2, Hn1b, Hn2b, Hsb, N);
  fused_agg<<<agb, 256, 0, stream>>>(Hsb, Hn1b, Hn2b, rp, rp2p, colC, inv, inv + N,
                                     part_s, part_q, N);
  bn_finalize<<<1, 128, 0, stream>>>(part_s, part_q, g2, b2, coef2, 1.0f / N);

  // ---- edge-label dots (bf16 gathers, BN affine fused) ----
  int db = (int)(((size_t)EL * 16 + 255) / 256);
  edge_dot_bn<<<db, 256, 0, stream>>>(Hsb, coef2, eli, eli + EL, out, EL);
}